// Round 1
// baseline (719.503 us; speedup 1.0000x reference)
//
#include <hip/hip_runtime.h>

#define EPS 0.01f

// ---------------- degree / dinv ----------------

__global__ void k_init_deg(float* __restrict__ degf, int n) {
    int i = blockIdx.x * blockDim.x + threadIdx.x;
    if (i < n) degf[i] = 1.0f;  // self-loop
}

__global__ void k_count(const int* __restrict__ dst, float* __restrict__ degf, int e) {
    int i = blockIdx.x * blockDim.x + threadIdx.x;
    if (i < e) atomicAdd(&degf[dst[i]], 1.0f);
}

__global__ void k_dinv(const float* __restrict__ degf, float* __restrict__ dinv, int n) {
    int i = blockIdx.x * blockDim.x + threadIdx.x;
    if (i < n) dinv[i] = rsqrtf(degf[i]);
}

// ---------------- GEMM1: hx = x @ W1   [N,16]@[16,64] ----------------
// block 256 = 4 rows x 64 cols
__global__ __launch_bounds__(256) void k_gemm1(const float* __restrict__ x,
                                               const float* __restrict__ W1,
                                               float* __restrict__ hx, int n) {
    __shared__ float w[16 * 64];
    int t = threadIdx.x;
    for (int i = t; i < 16 * 64; i += 256) w[i] = W1[i];
    __syncthreads();
    int row = blockIdx.x * 4 + (t >> 6);
    int col = t & 63;
    if (row < n) {
        const float* xr = x + (size_t)row * 16;
        float acc = 0.f;
#pragma unroll
        for (int k = 0; k < 16; ++k) acc += xr[k] * w[k * 64 + col];
        hx[(size_t)row * 64 + col] = acc;
    }
}

// ---------------- self-loop init: out[i,c] = hx[i,c] * dinv[i]^2 ----------------

__global__ void k_self64(const float* __restrict__ hx, const float* __restrict__ dinv,
                         float* __restrict__ out, int n) {
    long long idx = (long long)blockIdx.x * blockDim.x + threadIdx.x;
    if (idx < (long long)n * 64) {
        int row = (int)(idx >> 6);
        float d = dinv[row];
        out[idx] = hx[idx] * d * d;
    }
}

__global__ void k_self32(const float* __restrict__ hx, const float* __restrict__ dinv,
                         float* __restrict__ out, int n) {
    long long idx = (long long)blockIdx.x * blockDim.x + threadIdx.x;
    if (idx < (long long)n * 32) {
        int row = (int)(idx >> 5);
        float d = dinv[row];
        out[idx] = hx[idx] * d * d;
    }
}

// ---------------- edge scatter, 64 feats (4 edges / 256-block) ----------------

__global__ __launch_bounds__(256) void k_scatter64(const int* __restrict__ src,
                                                   const int* __restrict__ dst,
                                                   const float* __restrict__ dinv,
                                                   const float* __restrict__ hx,
                                                   float* __restrict__ out, int e) {
    int t = threadIdx.x;
    int eid = blockIdx.x * 4 + (t >> 6);
    int c = t & 63;
    if (eid < e) {
        int s = src[eid], d = dst[eid];
        float w = dinv[s] * dinv[d];
        atomicAdd(&out[(size_t)d * 64 + c], hx[(size_t)s * 64 + c] * w);
    }
}

// ---------------- edge scatter, 32 feats (8 edges / 256-block) ----------------

__global__ __launch_bounds__(256) void k_scatter32(const int* __restrict__ src,
                                                   const int* __restrict__ dst,
                                                   const float* __restrict__ dinv,
                                                   const float* __restrict__ hx,
                                                   float* __restrict__ out, int e) {
    int t = threadIdx.x;
    int eid = blockIdx.x * 8 + (t >> 5);
    int c = t & 31;
    if (eid < e) {
        int s = src[eid], d = dst[eid];
        float w = dinv[s] * dinv[d];
        atomicAdd(&out[(size_t)d * 32 + c], hx[(size_t)s * 32 + c] * w);
    }
}

// ---------------- GEMM2 fused: hx2 = relu(h1raw + b1) @ W3   [N,64]@[64,32] ----------------
// block 256 = 8 rows x 32 cols
__global__ __launch_bounds__(256) void k_gemm2(const float* __restrict__ h1raw,
                                               const float* __restrict__ W3,
                                               const float* __restrict__ b1,
                                               float* __restrict__ hx2, int n) {
    __shared__ float w[64 * 32];
    __shared__ float bs[64];
    __shared__ float tile[8 * 64];
    int t = threadIdx.x;
    for (int i = t; i < 64 * 32; i += 256) w[i] = W3[i];
    if (t < 64) bs[t] = b1[t];
    __syncthreads();
    int row0 = blockIdx.x * 8;
    for (int i = t; i < 8 * 64; i += 256) {
        int r = i >> 6, c = i & 63;
        int row = row0 + r;
        float v = (row < n) ? h1raw[(size_t)row * 64 + c] : 0.f;
        v += bs[c];
        tile[i] = v > 0.f ? v : 0.f;
    }
    __syncthreads();
    int r = t >> 5, m = t & 31;
    int row = row0 + r;
    if (row < n) {
        float acc = 0.f;
#pragma unroll
        for (int k = 0; k < 64; ++k) acc += tile[r * 64 + k] * w[k * 32 + m];
        hx2[(size_t)row * 32 + m] = acc;
    }
}

// ---------------- stats: h = relu(v + b3) in place, accumulate col sums ----------------

__global__ void k_zero_partials(float* __restrict__ p) {
    int t = threadIdx.x;
    if (t < 64) p[t] = 0.f;
}

__global__ __launch_bounds__(256) void k_stats(float* __restrict__ h,
                                               const float* __restrict__ b3,
                                               float* __restrict__ partial, int n) {
    int t = threadIdx.x;
    int c = t & 31;
    float bias = b3[c];
    float s = 0.f, sq = 0.f;
    long long total = (long long)n * 32;
    long long stride = (long long)gridDim.x * 256;
    for (long long idx = (long long)blockIdx.x * 256 + t; idx < total; idx += stride) {
        float v = h[idx] + bias;
        v = v > 0.f ? v : 0.f;
        h[idx] = v;
        s += v;
        sq += v * v;
    }
    __shared__ float ls[256], lq[256];
    ls[t] = s;
    lq[t] = sq;
    __syncthreads();
    if (t < 32) {
        float a = 0.f, b = 0.f;
#pragma unroll
        for (int r = 0; r < 8; ++r) {
            a += ls[r * 32 + t];
            b += lq[r * 32 + t];
        }
        atomicAdd(&partial[t], a);
        atomicAdd(&partial[32 + t], b);
    }
}

__global__ void k_finalize(const float* __restrict__ partial, float* __restrict__ meaninv, int n) {
    int t = threadIdx.x;
    if (t < 32) {
        float invn = 1.0f / (float)n;
        float mean = partial[t] * invn;
        float var = partial[32 + t] * invn - mean * mean;
        var = var > EPS ? var : EPS;
        meaninv[t] = mean;
        meaninv[32 + t] = rsqrtf(var);
    }
}

__global__ void k_norm(float* __restrict__ h, const float* __restrict__ meaninv, int n) {
    long long idx = (long long)blockIdx.x * blockDim.x + threadIdx.x;
    if (idx < (long long)n * 32) {
        int c = (int)(idx & 31);
        h[idx] = (h[idx] - meaninv[c]) * meaninv[32 + c];
    }
}

extern "C" void kernel_launch(void* const* d_in, const int* in_sizes, int n_in,
                              void* d_out, int out_size, void* d_ws, size_t ws_size,
                              hipStream_t stream) {
    const float* x  = (const float*)d_in[0];
    const int* ei   = (const int*)d_in[1];
    const float* W1 = (const float*)d_in[2];
    const float* b1 = (const float*)d_in[3];
    const float* W3 = (const float*)d_in[4];
    const float* b3 = (const float*)d_in[5];

    const int N = in_sizes[0] / 16;
    const int E = in_sizes[1] / 2;
    const int* src = ei;       // edge_index[0]
    const int* dst = ei + E;   // edge_index[1]

    float* ws = (float*)d_ws;
    float* degf    = ws;                 // N
    float* dinv    = degf + N;           // N
    float* bufA    = dinv + N;           // N*64  (hx1, later hx2)
    float* bufB    = bufA + (size_t)N * 64;  // N*64  (agg1)
    float* partial = bufB + (size_t)N * 64;  // 64
    float* meaninv = partial + 64;       // 64

    float* out = (float*)d_out;          // N*32

    // degrees
    k_init_deg<<<(N + 255) / 256, 256, 0, stream>>>(degf, N);
    k_count<<<(E + 255) / 256, 256, 0, stream>>>(dst, degf, E);
    k_dinv<<<(N + 255) / 256, 256, 0, stream>>>(degf, dinv, N);

    // layer 1
    k_gemm1<<<(N + 3) / 4, 256, 0, stream>>>(x, W1, bufA, N);
    k_self64<<<((long long)N * 64 + 255) / 256, 256, 0, stream>>>(bufA, dinv, bufB, N);
    k_scatter64<<<(E + 3) / 4, 256, 0, stream>>>(src, dst, dinv, bufA, bufB, E);

    // layer 2 (fused bias+relu of layer1 inside gemm2)
    k_gemm2<<<(N + 7) / 8, 256, 0, stream>>>(bufB, W3, b1, bufA, N);
    k_self32<<<((long long)N * 32 + 255) / 256, 256, 0, stream>>>(bufA, dinv, out, N);
    k_scatter32<<<(E + 7) / 8, 256, 0, stream>>>(src, dst, dinv, bufA, out, E);

    // normalizer
    k_zero_partials<<<1, 64, 0, stream>>>(partial);
    k_stats<<<1024, 256, 0, stream>>>(out, b3, partial, N);
    k_finalize<<<1, 64, 0, stream>>>(partial, meaninv, N);
    k_norm<<<((long long)N * 32 + 255) / 256, 256, 0, stream>>>(out, meaninv, N);
}

// Round 2
// 507.159 us; speedup vs baseline: 1.4187x; 1.4187x over previous
//
#include <hip/hip_runtime.h>

#define EPS 0.01f
#define SCAN_BS 512

// ---------------- degree histogram ----------------

__global__ void k_zero_int(int* __restrict__ p, int n) {
    int i = blockIdx.x * blockDim.x + threadIdx.x;
    if (i < n) p[i] = 0;
}

__global__ void k_hist(const int* __restrict__ dst, int* __restrict__ degi, int e) {
    int i = blockIdx.x * blockDim.x + threadIdx.x;
    if (i < e) atomicAdd(&degi[dst[i]], 1);
}

__global__ void k_dinv(const int* __restrict__ degi, float* __restrict__ dinv, int n) {
    int i = blockIdx.x * blockDim.x + threadIdx.x;
    if (i < n) dinv[i] = rsqrtf((float)degi[i] + 1.0f);  // +1 self-loop
}

// ---------------- exclusive scan (3-kernel, N <= 512*512) ----------------

__global__ __launch_bounds__(SCAN_BS) void k_scan_block(const int* __restrict__ degi,
                                                        int* __restrict__ rowstart,
                                                        int* __restrict__ bsum, int n) {
    __shared__ int sd[SCAN_BS];
    int t = threadIdx.x;
    int gid = blockIdx.x * SCAN_BS + t;
    int v = (gid < n) ? degi[gid] : 0;
    sd[t] = v;
    __syncthreads();
    for (int off = 1; off < SCAN_BS; off <<= 1) {
        int x = (t >= off) ? sd[t - off] : 0;
        __syncthreads();
        sd[t] += x;
        __syncthreads();
    }
    if (gid < n) rowstart[gid] = sd[t] - v;  // exclusive
    if (t == SCAN_BS - 1) bsum[blockIdx.x] = sd[t];
}

__global__ __launch_bounds__(SCAN_BS) void k_scan_tops(int* __restrict__ bsum, int nb) {
    __shared__ int sd[SCAN_BS];
    int t = threadIdx.x;
    int v = (t < nb) ? bsum[t] : 0;
    sd[t] = v;
    __syncthreads();
    for (int off = 1; off < SCAN_BS; off <<= 1) {
        int x = (t >= off) ? sd[t - off] : 0;
        __syncthreads();
        sd[t] += x;
        __syncthreads();
    }
    if (t < nb) bsum[t] = sd[t] - v;  // exclusive
}

__global__ __launch_bounds__(SCAN_BS) void k_scan_add(int* __restrict__ rowstart,
                                                      int* __restrict__ cursor,
                                                      const int* __restrict__ bsum, int n) {
    int gid = blockIdx.x * SCAN_BS + threadIdx.x;
    if (gid < n) {
        int rs = rowstart[gid] + bsum[blockIdx.x];
        rowstart[gid] = rs;
        cursor[gid] = rs;
    }
}

__global__ void k_fill(const int* __restrict__ src, const int* __restrict__ dst,
                       int* __restrict__ cursor, int* __restrict__ csr_src, int e) {
    int i = blockIdx.x * blockDim.x + threadIdx.x;
    if (i < e) {
        int d = dst[i];
        int pos = atomicAdd(&cursor[d], 1);
        csr_src[pos] = src[i];
    }
}

// ---------------- GEMM1: hx = x @ W1   [N,16]@[16,64] ----------------

__global__ __launch_bounds__(256) void k_gemm1(const float* __restrict__ x,
                                               const float* __restrict__ W1,
                                               float* __restrict__ hx, int n) {
    __shared__ float w[16 * 64];
    int t = threadIdx.x;
    for (int i = t; i < 16 * 64; i += 256) w[i] = W1[i];
    __syncthreads();
    int row = blockIdx.x * 4 + (t >> 6);
    int col = t & 63;
    if (row < n) {
        const float* xr = x + (size_t)row * 16;
        float acc = 0.f;
#pragma unroll
        for (int k = 0; k < 16; ++k) acc += xr[k] * w[k * 64 + col];
        hx[(size_t)row * 64 + col] = acc;
    }
}

// ---------------- gather 64 feats: 1 wave per node ----------------

__global__ __launch_bounds__(256) void k_gather64(const int* __restrict__ rowstart,
                                                  const int* __restrict__ degi,
                                                  const int* __restrict__ csr_src,
                                                  const float* __restrict__ dinv,
                                                  const float* __restrict__ hx,
                                                  float* __restrict__ out, int n) {
    int t = threadIdx.x;
    int node = blockIdx.x * 4 + (t >> 6);
    if (node >= n) return;
    int c = t & 63;
    float dn = dinv[node];
    float acc = hx[(size_t)node * 64 + c] * dn * dn;  // self-loop
    float acc2 = 0.f;
    const int* sp = csr_src + rowstart[node];
    int deg = degi[node];
    int k = 0;
    for (; k + 2 <= deg; k += 2) {
        int s0 = sp[k], s1 = sp[k + 1];
        acc  += hx[(size_t)s0 * 64 + c] * (dinv[s0] * dn);
        acc2 += hx[(size_t)s1 * 64 + c] * (dinv[s1] * dn);
    }
    if (k < deg) {
        int s0 = sp[k];
        acc += hx[(size_t)s0 * 64 + c] * (dinv[s0] * dn);
    }
    out[(size_t)node * 64 + c] = acc + acc2;
}

// ---------------- GEMM2 fused: hx2 = relu(h1raw + b1) @ W3 ----------------

__global__ __launch_bounds__(256) void k_gemm2(const float* __restrict__ h1raw,
                                               const float* __restrict__ W3,
                                               const float* __restrict__ b1,
                                               float* __restrict__ hx2, int n) {
    __shared__ float w[64 * 32];
    __shared__ float bs[64];
    __shared__ float tile[8 * 64];
    int t = threadIdx.x;
    for (int i = t; i < 64 * 32; i += 256) w[i] = W3[i];
    if (t < 64) bs[t] = b1[t];
    __syncthreads();
    int row0 = blockIdx.x * 8;
    for (int i = t; i < 8 * 64; i += 256) {
        int r = i >> 6, c = i & 63;
        int row = row0 + r;
        float v = (row < n) ? h1raw[(size_t)row * 64 + c] : 0.f;
        v += bs[c];
        tile[i] = v > 0.f ? v : 0.f;
    }
    __syncthreads();
    int r = t >> 5, m = t & 31;
    int row = row0 + r;
    if (row < n) {
        float acc = 0.f;
#pragma unroll
        for (int k = 0; k < 64; ++k) acc += tile[r * 64 + k] * w[k * 32 + m];
        hx2[(size_t)row * 32 + m] = acc;
    }
}

// ---------------- gather 32 feats + bias + relu + stats ----------------
// 1 wave per node (2 edges/iter via lane halves); 32 nodes per block.

__global__ __launch_bounds__(256) void k_gather32_stats(const int* __restrict__ rowstart,
                                                        const int* __restrict__ degi,
                                                        const int* __restrict__ csr_src,
                                                        const float* __restrict__ dinv,
                                                        const float* __restrict__ hx,
                                                        const float* __restrict__ b3,
                                                        float* __restrict__ out,
                                                        float* __restrict__ partial, int n) {
    int t = threadIdx.x;
    int lane = t & 63;
    int c = lane & 31;
    int half = lane >> 5;
    float bias = b3[c];
    float s_sum = 0.f, s_sq = 0.f;
    for (int it = 0; it < 8; ++it) {
        int node = blockIdx.x * 32 + it * 4 + (t >> 6);
        if (node < n) {
            float dn = dinv[node];
            float acc = half ? 0.f : hx[(size_t)node * 32 + c] * dn * dn;  // self-loop in half 0
            const int* sp = csr_src + rowstart[node];
            int deg = degi[node];
            for (int k = half; k < deg; k += 2) {
                int s = sp[k];
                acc += hx[(size_t)s * 32 + c] * (dinv[s] * dn);
            }
            acc += __shfl_xor(acc, 32);
            if (half == 0) {
                float v = acc + bias;
                v = v > 0.f ? v : 0.f;
                out[(size_t)node * 32 + c] = v;
                s_sum += v;
                s_sq += v * v;
            }
        }
    }
    __shared__ float ls[256], lq[256];
    ls[t] = s_sum;
    lq[t] = s_sq;
    __syncthreads();
    if (t < 32) {
        float a = 0.f, b = 0.f;
#pragma unroll
        for (int wv = 0; wv < 4; ++wv) {
            a += ls[wv * 64 + t];
            b += lq[wv * 64 + t];
        }
        atomicAdd(&partial[t], a);
        atomicAdd(&partial[32 + t], b);
    }
}

// ---------------- normalizer ----------------

__global__ void k_zero_partials(float* __restrict__ p) {
    int t = threadIdx.x;
    if (t < 64) p[t] = 0.f;
}

__global__ void k_finalize(const float* __restrict__ partial, float* __restrict__ meaninv, int n) {
    int t = threadIdx.x;
    if (t < 32) {
        float invn = 1.0f / (float)n;
        float mean = partial[t] * invn;
        float var = partial[32 + t] * invn - mean * mean;
        var = var > EPS ? var : EPS;
        meaninv[t] = mean;
        meaninv[32 + t] = rsqrtf(var);
    }
}

__global__ void k_norm(float* __restrict__ h, const float* __restrict__ meaninv, int n) {
    long long idx = (long long)blockIdx.x * blockDim.x + threadIdx.x;
    if (idx < (long long)n * 32) {
        int c = (int)(idx & 31);
        h[idx] = (h[idx] - meaninv[c]) * meaninv[32 + c];
    }
}

extern "C" void kernel_launch(void* const* d_in, const int* in_sizes, int n_in,
                              void* d_out, int out_size, void* d_ws, size_t ws_size,
                              hipStream_t stream) {
    const float* x  = (const float*)d_in[0];
    const int* ei   = (const int*)d_in[1];
    const float* W1 = (const float*)d_in[2];
    const float* b1 = (const float*)d_in[3];
    const float* W3 = (const float*)d_in[4];
    const float* b3 = (const float*)d_in[5];

    const int N = in_sizes[0] / 16;
    const int E = in_sizes[1] / 2;
    const int* src = ei;       // edge_index[0]
    const int* dst = ei + E;   // edge_index[1]

    char* ws = (char*)d_ws;
    int*   degi     = (int*)ws;                      ws += (size_t)N * 4;
    float* dinv     = (float*)ws;                    ws += (size_t)N * 4;
    int*   rowstart = (int*)ws;                      ws += (size_t)N * 4;
    int*   cursor   = (int*)ws;                      ws += (size_t)N * 4;
    int*   bsum     = (int*)ws;                      ws += (size_t)SCAN_BS * 4;
    int*   csr_src  = (int*)ws;                      ws += (size_t)E * 4;
    float* bufA     = (float*)ws;                    ws += (size_t)N * 64 * 4;
    float* bufB     = (float*)ws;                    ws += (size_t)N * 64 * 4;
    float* partial  = (float*)ws;                    ws += 64 * 4;
    float* meaninv  = (float*)ws;

    float* out = (float*)d_out;  // N*32

    const int NB = (N + SCAN_BS - 1) / SCAN_BS;  // <= 512

    // CSR build (shared by both layers)
    k_zero_int<<<(N + 255) / 256, 256, 0, stream>>>(degi, N);
    k_hist<<<(E + 255) / 256, 256, 0, stream>>>(dst, degi, E);
    k_dinv<<<(N + 255) / 256, 256, 0, stream>>>(degi, dinv, N);
    k_scan_block<<<NB, SCAN_BS, 0, stream>>>(degi, rowstart, bsum, N);
    k_scan_tops<<<1, SCAN_BS, 0, stream>>>(bsum, NB);
    k_scan_add<<<NB, SCAN_BS, 0, stream>>>(rowstart, cursor, bsum, N);
    k_fill<<<(E + 255) / 256, 256, 0, stream>>>(src, dst, cursor, csr_src, E);

    // layer 1
    k_gemm1<<<(N + 3) / 4, 256, 0, stream>>>(x, W1, bufA, N);
    k_gather64<<<(N + 3) / 4, 256, 0, stream>>>(rowstart, degi, csr_src, dinv, bufA, bufB, N);

    // layer 2
    k_gemm2<<<(N + 7) / 8, 256, 0, stream>>>(bufB, W3, b1, bufA, N);
    k_zero_partials<<<1, 64, 0, stream>>>(partial);
    k_gather32_stats<<<(N + 31) / 32, 256, 0, stream>>>(rowstart, degi, csr_src, dinv, bufA,
                                                        b3, out, partial, N);

    // normalizer
    k_finalize<<<1, 64, 0, stream>>>(partial, meaninv, N);
    k_norm<<<((long long)N * 32 + 255) / 256, 256, 0, stream>>>(out, meaninv, N);
}

// Round 3
// 406.631 us; speedup vs baseline: 1.7694x; 1.2472x over previous
//
#include <hip/hip_runtime.h>

#define EPS 0.01f
#define SCAN_BS 512

// ---------------- degree histogram / dinv ----------------

__global__ void k_zero_int(int* __restrict__ p, int n) {
    int i = blockIdx.x * blockDim.x + threadIdx.x;
    if (i < n) p[i] = 0;
}

__global__ void k_hist(const int* __restrict__ dst, int* __restrict__ degi, int e) {
    int i = blockIdx.x * blockDim.x + threadIdx.x;
    if (i < e) atomicAdd(&degi[dst[i]], 1);
}

__global__ void k_dinv(const int* __restrict__ degi, float* __restrict__ dinv, int n) {
    int i = blockIdx.x * blockDim.x + threadIdx.x;
    if (i < n) dinv[i] = rsqrtf((float)degi[i] + 1.0f);  // +1 self-loop
}

// ---------------- exclusive scan (3-kernel, N <= 512*512) ----------------

__global__ __launch_bounds__(SCAN_BS) void k_scan_block(const int* __restrict__ degi,
                                                        int* __restrict__ rowstart,
                                                        int* __restrict__ bsum, int n) {
    __shared__ int sd[SCAN_BS];
    int t = threadIdx.x;
    int gid = blockIdx.x * SCAN_BS + t;
    int v = (gid < n) ? degi[gid] : 0;
    sd[t] = v;
    __syncthreads();
    for (int off = 1; off < SCAN_BS; off <<= 1) {
        int x = (t >= off) ? sd[t - off] : 0;
        __syncthreads();
        sd[t] += x;
        __syncthreads();
    }
    if (gid < n) rowstart[gid] = sd[t] - v;  // exclusive
    if (t == SCAN_BS - 1) bsum[blockIdx.x] = sd[t];
}

__global__ __launch_bounds__(SCAN_BS) void k_scan_tops(int* __restrict__ bsum, int nb) {
    __shared__ int sd[SCAN_BS];
    int t = threadIdx.x;
    int v = (t < nb) ? bsum[t] : 0;
    sd[t] = v;
    __syncthreads();
    for (int off = 1; off < SCAN_BS; off <<= 1) {
        int x = (t >= off) ? sd[t - off] : 0;
        __syncthreads();
        sd[t] += x;
        __syncthreads();
    }
    if (t < nb) bsum[t] = sd[t] - v;  // exclusive
}

__global__ __launch_bounds__(SCAN_BS) void k_scan_add(int* __restrict__ rowstart,
                                                      int* __restrict__ cursor,
                                                      const int* __restrict__ bsum, int n) {
    int gid = blockIdx.x * SCAN_BS + threadIdx.x;
    if (gid < n) {
        int rs = rowstart[gid] + bsum[blockIdx.x];
        rowstart[gid] = rs;
        cursor[gid] = rs;
    }
}

__global__ void k_fill(const int* __restrict__ src, const int* __restrict__ dst,
                       int* __restrict__ cursor, int* __restrict__ csr_src, int e) {
    int i = blockIdx.x * blockDim.x + threadIdx.x;
    if (i < e) {
        int d = dst[i];
        int pos = atomicAdd(&cursor[d], 1);
        csr_src[pos] = src[i];
    }
}

// ---------------- gather in 16-dim input space: agg = \hat{A} x ----------------
// 1 wave per node; 4 edge-slots of 16 lanes; 2-way unroll per slot.

__global__ __launch_bounds__(256) void k_gather16(const int* __restrict__ rowstart,
                                                  const int* __restrict__ degi,
                                                  const int* __restrict__ csr_src,
                                                  const float* __restrict__ dinv,
                                                  const float* __restrict__ x,
                                                  float* __restrict__ out, int n) {
    int t = threadIdx.x;
    int node = blockIdx.x * 4 + (t >> 6);
    if (node >= n) return;
    int lane = t & 63;
    int c = lane & 15;
    int slot = lane >> 4;  // 0..3
    float dn = dinv[node];
    const int* sp = csr_src + rowstart[node];
    int deg = degi[node];
    float e0 = 0.f, e1 = 0.f;
    int k = slot;
    for (; k + 4 < deg; k += 8) {
        int s0 = sp[k], s1 = sp[k + 4];
        e0 += x[(size_t)s0 * 16 + c] * dinv[s0];
        e1 += x[(size_t)s1 * 16 + c] * dinv[s1];
    }
    if (k < deg) {
        int s0 = sp[k];
        e0 += x[(size_t)s0 * 16 + c] * dinv[s0];
    }
    float acc = e0 + e1;
    acc += __shfl_xor(acc, 16);
    acc += __shfl_xor(acc, 32);
    if (slot == 0)
        out[(size_t)node * 16 + c] = dn * acc + dn * dn * x[(size_t)node * 16 + c];
}

// ---------------- fused MLP: h2 = relu(agg@W1 + b1) @ W3,  16 rows/block ----------------

__global__ __launch_bounds__(256) void k_mlp(const float* __restrict__ agg,
                                             const float* __restrict__ W1,
                                             const float* __restrict__ b1,
                                             const float* __restrict__ W3,
                                             float* __restrict__ h2, int n) {
    __shared__ float w1[16 * 64];
    __shared__ float w3[64 * 32];
    __shared__ float bs[64];
    __shared__ float a[16 * 16];
    __shared__ float z[16 * 64];
    int t = threadIdx.x;
    for (int i = t; i < 16 * 64; i += 256) w1[i] = W1[i];
    for (int i = t; i < 64 * 32; i += 256) w3[i] = W3[i];
    if (t < 64) bs[t] = b1[t];
    int row0 = blockIdx.x * 16;
    {
        int r = t >> 4, c = t & 15;
        int row = row0 + r;
        a[t] = (row < n) ? agg[(size_t)row * 16 + c] : 0.f;
    }
    __syncthreads();
    // z = relu(a @ W1 + b1): 16x64
    for (int i = t; i < 1024; i += 256) {
        int r = i >> 6, c = i & 63;
        float acc = bs[c];
#pragma unroll
        for (int k = 0; k < 16; ++k) acc += a[r * 16 + k] * w1[k * 64 + c];
        z[i] = acc > 0.f ? acc : 0.f;
    }
    __syncthreads();
    // h2 = z @ W3: 16x32
    for (int i = t; i < 512; i += 256) {
        int r = i >> 5, c = i & 31;
        float acc = 0.f;
#pragma unroll
        for (int k = 0; k < 64; ++k) acc += z[r * 64 + k] * w3[k * 32 + c];
        int row = row0 + r;
        if (row < n) h2[(size_t)row * 32 + c] = acc;
    }
}

// ---------------- gather 32 feats + bias + relu + stats ----------------
// 1 wave per node; 2 edge-slots of 32 lanes; 2-way unroll per slot.

__global__ __launch_bounds__(256) void k_gather32_stats(const int* __restrict__ rowstart,
                                                        const int* __restrict__ degi,
                                                        const int* __restrict__ csr_src,
                                                        const float* __restrict__ dinv,
                                                        const float* __restrict__ hx,
                                                        const float* __restrict__ b3,
                                                        float* __restrict__ out,
                                                        float* __restrict__ partial, int n) {
    int t = threadIdx.x;
    int lane = t & 63;
    int c = lane & 31;
    int half = lane >> 5;
    float bias = b3[c];
    float s_sum = 0.f, s_sq = 0.f;
    for (int it = 0; it < 8; ++it) {
        int node = blockIdx.x * 32 + it * 4 + (t >> 6);
        if (node < n) {
            float dn = dinv[node];
            const int* sp = csr_src + rowstart[node];
            int deg = degi[node];
            float e0 = 0.f, e1 = 0.f;
            int k = half;
            for (; k + 2 < deg; k += 4) {
                int s0 = sp[k], s1 = sp[k + 2];
                e0 += hx[(size_t)s0 * 32 + c] * dinv[s0];
                e1 += hx[(size_t)s1 * 32 + c] * dinv[s1];
            }
            if (k < deg) {
                int s0 = sp[k];
                e0 += hx[(size_t)s0 * 32 + c] * dinv[s0];
            }
            float acc = e0 + e1;
            acc += __shfl_xor(acc, 32);
            if (half == 0) {
                float v = dn * acc + dn * dn * hx[(size_t)node * 32 + c] + bias;
                v = v > 0.f ? v : 0.f;
                out[(size_t)node * 32 + c] = v;
                s_sum += v;
                s_sq += v * v;
            }
        }
    }
    __shared__ float ls[256], lq[256];
    ls[t] = s_sum;
    lq[t] = s_sq;
    __syncthreads();
    if (t < 32) {
        float a = 0.f, b = 0.f;
#pragma unroll
        for (int wv = 0; wv < 4; ++wv) {
            a += ls[wv * 64 + t];
            b += lq[wv * 64 + t];
        }
        atomicAdd(&partial[t], a);
        atomicAdd(&partial[32 + t], b);
    }
}

// ---------------- normalizer ----------------

__global__ void k_zero_partials(float* __restrict__ p) {
    int t = threadIdx.x;
    if (t < 64) p[t] = 0.f;
}

__global__ void k_finalize(const float* __restrict__ partial, float* __restrict__ meaninv, int n) {
    int t = threadIdx.x;
    if (t < 32) {
        float invn = 1.0f / (float)n;
        float mean = partial[t] * invn;
        float var = partial[32 + t] * invn - mean * mean;
        var = var > EPS ? var : EPS;
        meaninv[t] = mean;
        meaninv[32 + t] = rsqrtf(var);
    }
}

__global__ void k_norm(float* __restrict__ h, const float* __restrict__ meaninv, int n) {
    long long idx = (long long)blockIdx.x * blockDim.x + threadIdx.x;
    if (idx < (long long)n * 32) {
        int c = (int)(idx & 31);
        h[idx] = (h[idx] - meaninv[c]) * meaninv[32 + c];
    }
}

extern "C" void kernel_launch(void* const* d_in, const int* in_sizes, int n_in,
                              void* d_out, int out_size, void* d_ws, size_t ws_size,
                              hipStream_t stream) {
    const float* x  = (const float*)d_in[0];
    const int* ei   = (const int*)d_in[1];
    const float* W1 = (const float*)d_in[2];
    const float* b1 = (const float*)d_in[3];
    const float* W3 = (const float*)d_in[4];
    const float* b3 = (const float*)d_in[5];

    const int N = in_sizes[0] / 16;
    const int E = in_sizes[1] / 2;
    const int* src = ei;       // edge_index[0]
    const int* dst = ei + E;   // edge_index[1]

    char* ws = (char*)d_ws;
    int*   degi     = (int*)ws;                      ws += (size_t)N * 4;
    float* dinv     = (float*)ws;                    ws += (size_t)N * 4;
    int*   rowstart = (int*)ws;                      ws += (size_t)N * 4;
    int*   cursor   = (int*)ws;                      ws += (size_t)N * 4;
    int*   bsum     = (int*)ws;                      ws += (size_t)SCAN_BS * 4;
    int*   csr_src  = (int*)ws;                      ws += (size_t)E * 4;
    float* aggX     = (float*)ws;                    ws += (size_t)N * 16 * 4;
    float* h2pre    = (float*)ws;                    ws += (size_t)N * 32 * 4;
    float* partial  = (float*)ws;                    ws += 64 * 4;
    float* meaninv  = (float*)ws;

    float* out = (float*)d_out;  // N*32

    const int NB = (N + SCAN_BS - 1) / SCAN_BS;  // <= 512

    // CSR build (shared by both layers)
    k_zero_int<<<(N + 255) / 256, 256, 0, stream>>>(degi, N);
    k_hist<<<(E + 255) / 256, 256, 0, stream>>>(dst, degi, E);
    k_dinv<<<(N + 255) / 256, 256, 0, stream>>>(degi, dinv, N);
    k_scan_block<<<NB, SCAN_BS, 0, stream>>>(degi, rowstart, bsum, N);
    k_scan_tops<<<1, SCAN_BS, 0, stream>>>(bsum, NB);
    k_scan_add<<<NB, SCAN_BS, 0, stream>>>(rowstart, cursor, bsum, N);
    k_fill<<<(E + 255) / 256, 256, 0, stream>>>(src, dst, cursor, csr_src, E);

    // layer 1 aggregation in input space, then fused MLP (gemm1+relu+gemm2)
    k_gather16<<<(N + 3) / 4, 256, 0, stream>>>(rowstart, degi, csr_src, dinv, x, aggX, N);
    k_mlp<<<(N + 15) / 16, 256, 0, stream>>>(aggX, W1, b1, W3, h2pre, N);

    // layer 2 aggregation + bias + relu + stats
    k_zero_partials<<<1, 64, 0, stream>>>(partial);
    k_gather32_stats<<<(N + 31) / 32, 256, 0, stream>>>(rowstart, degi, csr_src, dinv, h2pre,
                                                        b3, out, partial, N);

    // normalizer
    k_finalize<<<1, 64, 0, stream>>>(partial, meaninv, N);
    k_norm<<<((long long)N * 32 + 255) / 256, 256, 0, stream>>>(out, meaninv, N);
}

// Round 4
// 298.980 us; speedup vs baseline: 2.4065x; 1.3601x over previous
//
#include <hip/hip_runtime.h>

#define EPS 0.01f
#define SCAN_BS 512
#define NCHUNKS 256
#define BUCKET_SHIFT 9
#define BUCKET_SZ (1 << BUCKET_SHIFT)

// ---------------- degree histogram / dinv ----------------

__global__ void k_zero_int(int* __restrict__ p, int n) {
    int i = blockIdx.x * blockDim.x + threadIdx.x;
    if (i < n) p[i] = 0;
}

__global__ void k_hist(const int* __restrict__ dst, int* __restrict__ degi, int e) {
    int i = blockIdx.x * blockDim.x + threadIdx.x;
    if (i < e) atomicAdd(&degi[dst[i]], 1);
}

__global__ void k_dinv(const int* __restrict__ degi, float* __restrict__ dinv, int n) {
    int i = blockIdx.x * blockDim.x + threadIdx.x;
    if (i < n) dinv[i] = rsqrtf((float)degi[i] + 1.0f);  // +1 self-loop
}

// ---------------- exclusive scan (3-kernel, n <= 512*512) ----------------

__global__ __launch_bounds__(SCAN_BS) void k_scan_block(const int* __restrict__ in,
                                                        int* __restrict__ out,
                                                        int* __restrict__ bsum, int n) {
    __shared__ int sd[SCAN_BS];
    int t = threadIdx.x;
    int gid = blockIdx.x * SCAN_BS + t;
    int v = (gid < n) ? in[gid] : 0;
    sd[t] = v;
    __syncthreads();
    for (int off = 1; off < SCAN_BS; off <<= 1) {
        int x = (t >= off) ? sd[t - off] : 0;
        __syncthreads();
        sd[t] += x;
        __syncthreads();
    }
    if (gid < n) out[gid] = sd[t] - v;  // exclusive
    if (t == SCAN_BS - 1) bsum[blockIdx.x] = sd[t];
}

__global__ __launch_bounds__(SCAN_BS) void k_scan_tops(int* __restrict__ bsum, int nb) {
    __shared__ int sd[SCAN_BS];
    int t = threadIdx.x;
    int v = (t < nb) ? bsum[t] : 0;
    sd[t] = v;
    __syncthreads();
    for (int off = 1; off < SCAN_BS; off <<= 1) {
        int x = (t >= off) ? sd[t - off] : 0;
        __syncthreads();
        sd[t] += x;
        __syncthreads();
    }
    if (t < nb) bsum[t] = sd[t] - v;  // exclusive
}

__global__ __launch_bounds__(SCAN_BS) void k_scan_add(int* __restrict__ out,
                                                      const int* __restrict__ bsum, int n) {
    int gid = blockIdx.x * SCAN_BS + threadIdx.x;
    if (gid < n) out[gid] += bsum[blockIdx.x];
}

// ---------------- bucketed edge sort (fixes csr-fill write amplification) ----------------
// Pass A: per-chunk histogram over 512-node buckets.

__global__ __launch_bounds__(256) void kA_bucket_hist(const int* __restrict__ dst,
                                                      int* __restrict__ bh, int e,
                                                      int nbuck, int ce) {
    extern __shared__ int hist[];  // nbuck
    int b = blockIdx.x, t = threadIdx.x;
    for (int i = t; i < nbuck; i += 256) hist[i] = 0;
    __syncthreads();
    int lo = b * ce, hi = min(lo + ce, e);
    for (int i = lo + t; i < hi; i += 256) atomicAdd(&hist[dst[i] >> BUCKET_SHIFT], 1);
    __syncthreads();
    for (int i = t; i < nbuck; i += 256) bh[i * NCHUNKS + b] = hist[i];  // [bucket][chunk]
}

// Pass C: scatter packed (dst,src) records into bucket-major order.
// Each (block,bucket) segment is written by exactly one block -> full-line writebacks.

__global__ __launch_bounds__(256) void kC_bucket_scatter(const int* __restrict__ src,
                                                         const int* __restrict__ dst,
                                                         const int* __restrict__ bhs,
                                                         long long* __restrict__ eb, int e,
                                                         int nbuck, int ce) {
    extern __shared__ int cur[];  // nbuck
    int b = blockIdx.x, t = threadIdx.x;
    for (int i = t; i < nbuck; i += 256) cur[i] = bhs[i * NCHUNKS + b];
    __syncthreads();
    int lo = b * ce, hi = min(lo + ce, e);
    for (int i = lo + t; i < hi; i += 256) {
        int s = src[i], d = dst[i];
        int pos = atomicAdd(&cur[d >> BUCKET_SHIFT], 1);
        eb[pos] = ((long long)d << 32) | (unsigned int)s;
    }
}

// Pass D: one block per bucket; LDS cursors; csr region is block-exclusive.

__global__ __launch_bounds__(256) void kD_fill(const long long* __restrict__ eb,
                                               const int* __restrict__ bhs,
                                               const int* __restrict__ rowstart,
                                               int* __restrict__ csr_src,
                                               int n, int nbuck, int e) {
    __shared__ int cur[BUCKET_SZ];
    int k = blockIdx.x, t = threadIdx.x;
    int node0 = k << BUCKET_SHIFT;
    for (int i = t; i < BUCKET_SZ; i += 256) {
        int node = node0 + i;
        cur[i] = (node < n) ? rowstart[node] : 0;
    }
    __syncthreads();
    int lo = bhs[k * NCHUNKS];
    int hi = (k + 1 < nbuck) ? bhs[(k + 1) * NCHUNKS] : e;
    for (int i = lo + t; i < hi; i += 256) {
        long long p = eb[i];
        int d = (int)(p >> 32);
        int s = (int)(p & 0xffffffffLL);
        int pos = atomicAdd(&cur[d - node0], 1);
        csr_src[pos] = s;
    }
}

// ---------------- gather in 16-dim input space: agg = \hat{A} x ----------------

__global__ __launch_bounds__(256) void k_gather16(const int* __restrict__ rowstart,
                                                  const int* __restrict__ degi,
                                                  const int* __restrict__ csr_src,
                                                  const float* __restrict__ dinv,
                                                  const float* __restrict__ x,
                                                  float* __restrict__ out, int n) {
    int t = threadIdx.x;
    int node = blockIdx.x * 4 + (t >> 6);
    if (node >= n) return;
    int lane = t & 63;
    int c = lane & 15;
    int slot = lane >> 4;  // 0..3
    float dn = dinv[node];
    const int* sp = csr_src + rowstart[node];
    int deg = degi[node];
    float e0 = 0.f, e1 = 0.f;
    int k = slot;
    for (; k + 4 < deg; k += 8) {
        int s0 = sp[k], s1 = sp[k + 4];
        e0 += x[(size_t)s0 * 16 + c] * dinv[s0];
        e1 += x[(size_t)s1 * 16 + c] * dinv[s1];
    }
    if (k < deg) {
        int s0 = sp[k];
        e0 += x[(size_t)s0 * 16 + c] * dinv[s0];
    }
    float acc = e0 + e1;
    acc += __shfl_xor(acc, 16);
    acc += __shfl_xor(acc, 32);
    if (slot == 0)
        out[(size_t)node * 16 + c] = dn * acc + dn * dn * x[(size_t)node * 16 + c];
}

// ---------------- fused MLP: h2 = relu(agg@W1 + b1) @ W3,  16 rows/block ----------------

__global__ __launch_bounds__(256) void k_mlp(const float* __restrict__ agg,
                                             const float* __restrict__ W1,
                                             const float* __restrict__ b1,
                                             const float* __restrict__ W3,
                                             float* __restrict__ h2, int n) {
    __shared__ float w1[16 * 64];
    __shared__ float w3[64 * 32];
    __shared__ float bs[64];
    __shared__ float a[16 * 16];
    __shared__ float z[16 * 64];
    int t = threadIdx.x;
    for (int i = t; i < 16 * 64; i += 256) w1[i] = W1[i];
    for (int i = t; i < 64 * 32; i += 256) w3[i] = W3[i];
    if (t < 64) bs[t] = b1[t];
    int row0 = blockIdx.x * 16;
    {
        int r = t >> 4, c = t & 15;
        int row = row0 + r;
        a[t] = (row < n) ? agg[(size_t)row * 16 + c] : 0.f;
    }
    __syncthreads();
    for (int i = t; i < 1024; i += 256) {
        int r = i >> 6, c = i & 63;
        float acc = bs[c];
#pragma unroll
        for (int k = 0; k < 16; ++k) acc += a[r * 16 + k] * w1[k * 64 + c];
        z[i] = acc > 0.f ? acc : 0.f;
    }
    __syncthreads();
    for (int i = t; i < 512; i += 256) {
        int r = i >> 5, c = i & 31;
        float acc = 0.f;
#pragma unroll
        for (int k = 0; k < 64; ++k) acc += z[r * 64 + k] * w3[k * 32 + c];
        int row = row0 + r;
        if (row < n) h2[(size_t)row * 32 + c] = acc;
    }
}

// ---------------- gather 32 feats + bias + relu + stats ----------------

__global__ __launch_bounds__(256) void k_gather32_stats(const int* __restrict__ rowstart,
                                                        const int* __restrict__ degi,
                                                        const int* __restrict__ csr_src,
                                                        const float* __restrict__ dinv,
                                                        const float* __restrict__ hx,
                                                        const float* __restrict__ b3,
                                                        float* __restrict__ out,
                                                        float* __restrict__ partial, int n) {
    int t = threadIdx.x;
    int lane = t & 63;
    int c = lane & 31;
    int half = lane >> 5;
    float bias = b3[c];
    float s_sum = 0.f, s_sq = 0.f;
    for (int it = 0; it < 8; ++it) {
        int node = blockIdx.x * 32 + it * 4 + (t >> 6);
        if (node < n) {
            float dn = dinv[node];
            const int* sp = csr_src + rowstart[node];
            int deg = degi[node];
            float e0 = 0.f, e1 = 0.f;
            int k = half;
            for (; k + 2 < deg; k += 4) {
                int s0 = sp[k], s1 = sp[k + 2];
                e0 += hx[(size_t)s0 * 32 + c] * dinv[s0];
                e1 += hx[(size_t)s1 * 32 + c] * dinv[s1];
            }
            if (k < deg) {
                int s0 = sp[k];
                e0 += hx[(size_t)s0 * 32 + c] * dinv[s0];
            }
            float acc = e0 + e1;
            acc += __shfl_xor(acc, 32);
            if (half == 0) {
                float v = dn * acc + dn * dn * hx[(size_t)node * 32 + c] + bias;
                v = v > 0.f ? v : 0.f;
                out[(size_t)node * 32 + c] = v;
                s_sum += v;
                s_sq += v * v;
            }
        }
    }
    __shared__ float ls[256], lq[256];
    ls[t] = s_sum;
    lq[t] = s_sq;
    __syncthreads();
    if (t < 32) {
        float a = 0.f, b = 0.f;
#pragma unroll
        for (int wv = 0; wv < 4; ++wv) {
            a += ls[wv * 64 + t];
            b += lq[wv * 64 + t];
        }
        atomicAdd(&partial[t], a);
        atomicAdd(&partial[32 + t], b);
    }
}

// ---------------- normalizer ----------------

__global__ void k_zero_partials(float* __restrict__ p) {
    int t = threadIdx.x;
    if (t < 64) p[t] = 0.f;
}

__global__ void k_finalize(const float* __restrict__ partial, float* __restrict__ meaninv, int n) {
    int t = threadIdx.x;
    if (t < 32) {
        float invn = 1.0f / (float)n;
        float mean = partial[t] * invn;
        float var = partial[32 + t] * invn - mean * mean;
        var = var > EPS ? var : EPS;
        meaninv[t] = mean;
        meaninv[32 + t] = rsqrtf(var);
    }
}

__global__ void k_norm(float* __restrict__ h, const float* __restrict__ meaninv, int n) {
    long long idx = (long long)blockIdx.x * blockDim.x + threadIdx.x;
    if (idx < (long long)n * 32) {
        int c = (int)(idx & 31);
        h[idx] = (h[idx] - meaninv[c]) * meaninv[32 + c];
    }
}

extern "C" void kernel_launch(void* const* d_in, const int* in_sizes, int n_in,
                              void* d_out, int out_size, void* d_ws, size_t ws_size,
                              hipStream_t stream) {
    const float* x  = (const float*)d_in[0];
    const int* ei   = (const int*)d_in[1];
    const float* W1 = (const float*)d_in[2];
    const float* b1 = (const float*)d_in[3];
    const float* W3 = (const float*)d_in[4];
    const float* b3 = (const float*)d_in[5];

    const int N = in_sizes[0] / 16;
    const int E = in_sizes[1] / 2;
    const int* src = ei;       // edge_index[0]
    const int* dst = ei + E;   // edge_index[1]

    const int NBUCK = (N + BUCKET_SZ - 1) >> BUCKET_SHIFT;  // 196 for N=100000
    const int CE = (E + NCHUNKS - 1) / NCHUNKS;
    const int BH_TOTAL = NBUCK * NCHUNKS;

    char* ws = (char*)d_ws;
    int*   degi     = (int*)ws;       ws += (size_t)N * 4;
    float* dinv     = (float*)ws;     ws += (size_t)N * 4;
    int*   rowstart = (int*)ws;       ws += (size_t)N * 4;
    int*   bsum     = (int*)ws;       ws += (size_t)SCAN_BS * 4;
    int*   bsum2    = (int*)ws;       ws += (size_t)SCAN_BS * 4;
    int*   bh       = (int*)ws;       ws += (size_t)BH_TOTAL * 4;
    int*   bhs      = (int*)ws;       ws += (size_t)BH_TOTAL * 4;
    long long* eb   = (long long*)ws; ws += (size_t)E * 8;
    int*   csr_src  = (int*)ws;       ws += (size_t)E * 4;
    float* aggX     = (float*)ws;     ws += (size_t)N * 16 * 4;
    float* h2pre    = (float*)ws;     ws += (size_t)N * 32 * 4;
    float* partial  = (float*)ws;     ws += 64 * 4;
    float* meaninv  = (float*)ws;

    float* out = (float*)d_out;  // N*32

    const int NB = (N + SCAN_BS - 1) / SCAN_BS;
    const int NB2 = (BH_TOTAL + SCAN_BS - 1) / SCAN_BS;

    // degrees + rowstart
    k_zero_int<<<(N + 255) / 256, 256, 0, stream>>>(degi, N);
    k_hist<<<(E + 255) / 256, 256, 0, stream>>>(dst, degi, E);
    k_dinv<<<(N + 255) / 256, 256, 0, stream>>>(degi, dinv, N);
    k_scan_block<<<NB, SCAN_BS, 0, stream>>>(degi, rowstart, bsum, N);
    k_scan_tops<<<1, SCAN_BS, 0, stream>>>(bsum, NB);
    k_scan_add<<<NB, SCAN_BS, 0, stream>>>(rowstart, bsum, N);

    // bucketed edge sort + csr fill
    kA_bucket_hist<<<NCHUNKS, 256, NBUCK * 4, stream>>>(dst, bh, E, NBUCK, CE);
    k_scan_block<<<NB2, SCAN_BS, 0, stream>>>(bh, bhs, bsum2, BH_TOTAL);
    k_scan_tops<<<1, SCAN_BS, 0, stream>>>(bsum2, NB2);
    k_scan_add<<<NB2, SCAN_BS, 0, stream>>>(bhs, bsum2, BH_TOTAL);
    kC_bucket_scatter<<<NCHUNKS, 256, NBUCK * 4, stream>>>(src, dst, bhs, eb, E, NBUCK, CE);
    kD_fill<<<NBUCK, 256, 0, stream>>>(eb, bhs, rowstart, csr_src, N, NBUCK, E);

    // layer 1 aggregation in input space, then fused MLP
    k_gather16<<<(N + 3) / 4, 256, 0, stream>>>(rowstart, degi, csr_src, dinv, x, aggX, N);
    k_mlp<<<(N + 15) / 16, 256, 0, stream>>>(aggX, W1, b1, W3, h2pre, N);

    // layer 2 aggregation + bias + relu + stats
    k_zero_partials<<<1, 64, 0, stream>>>(partial);
    k_gather32_stats<<<(N + 31) / 32, 256, 0, stream>>>(rowstart, degi, csr_src, dinv, h2pre,
                                                        b3, out, partial, N);

    // normalizer
    k_finalize<<<1, 64, 0, stream>>>(partial, meaninv, N);
    k_norm<<<((long long)N * 32 + 255) / 256, 256, 0, stream>>>(out, meaninv, N);
}

// Round 5
// 289.174 us; speedup vs baseline: 2.4881x; 1.0339x over previous
//
#include <hip/hip_runtime.h>
#include <hip/hip_fp16.h>

#define EPS 0.01f
#define SCAN_BS 512
#define NCHUNKS 256
#define BUCKET_SHIFT 9
#define BUCKET_SZ (1 << BUCKET_SHIFT)

// ---------------- degree histogram / dinv ----------------

__global__ void k_zero_int(int* __restrict__ p, int n) {
    int i = blockIdx.x * blockDim.x + threadIdx.x;
    if (i < n) p[i] = 0;
}

__global__ void k_hist(const int* __restrict__ dst, int* __restrict__ degi, int e) {
    int i = blockIdx.x * blockDim.x + threadIdx.x;
    if (i < e) atomicAdd(&degi[dst[i]], 1);
}

__global__ void k_dinv(const int* __restrict__ degi, float* __restrict__ dinv, int n) {
    int i = blockIdx.x * blockDim.x + threadIdx.x;
    if (i < n) dinv[i] = rsqrtf((float)degi[i] + 1.0f);  // +1 self-loop
}

// ---------------- exclusive scan (3-kernel, n <= 512*512) ----------------

__global__ __launch_bounds__(SCAN_BS) void k_scan_block(const int* __restrict__ in,
                                                        int* __restrict__ out,
                                                        int* __restrict__ bsum, int n) {
    __shared__ int sd[SCAN_BS];
    int t = threadIdx.x;
    int gid = blockIdx.x * SCAN_BS + t;
    int v = (gid < n) ? in[gid] : 0;
    sd[t] = v;
    __syncthreads();
    for (int off = 1; off < SCAN_BS; off <<= 1) {
        int x = (t >= off) ? sd[t - off] : 0;
        __syncthreads();
        sd[t] += x;
        __syncthreads();
    }
    if (gid < n) out[gid] = sd[t] - v;  // exclusive
    if (t == SCAN_BS - 1) bsum[blockIdx.x] = sd[t];
}

__global__ __launch_bounds__(SCAN_BS) void k_scan_tops(int* __restrict__ bsum, int nb) {
    __shared__ int sd[SCAN_BS];
    int t = threadIdx.x;
    int v = (t < nb) ? bsum[t] : 0;
    sd[t] = v;
    __syncthreads();
    for (int off = 1; off < SCAN_BS; off <<= 1) {
        int x = (t >= off) ? sd[t - off] : 0;
        __syncthreads();
        sd[t] += x;
        __syncthreads();
    }
    if (t < nb) bsum[t] = sd[t] - v;  // exclusive
}

__global__ __launch_bounds__(SCAN_BS) void k_scan_add(int* __restrict__ out,
                                                      const int* __restrict__ bsum, int n) {
    int gid = blockIdx.x * SCAN_BS + threadIdx.x;
    if (gid < n) out[gid] += bsum[blockIdx.x];
}

// ---------------- bucketed edge sort ----------------
// Pass A: per-chunk histogram over 512-node buckets.

__global__ __launch_bounds__(256) void kA_bucket_hist(const int* __restrict__ dst,
                                                      int* __restrict__ bh, int e,
                                                      int nbuck, int ce) {
    extern __shared__ int hist[];  // nbuck
    int b = blockIdx.x, t = threadIdx.x;
    for (int i = t; i < nbuck; i += 256) hist[i] = 0;
    __syncthreads();
    int lo = b * ce, hi = min(lo + ce, e);
    for (int i = lo + t; i < hi; i += 256) atomicAdd(&hist[dst[i] >> BUCKET_SHIFT], 1);
    __syncthreads();
    for (int i = t; i < nbuck; i += 256) bh[i * NCHUNKS + b] = hist[i];  // [bucket][chunk]
}

// Pass C: scatter packed (d_local<<23 | src) 4B records into bucket-major order.
// Each (block,bucket) segment is written by exactly one block -> full-line writebacks.

__global__ __launch_bounds__(256) void kC_bucket_scatter(const int* __restrict__ src,
                                                         const int* __restrict__ dst,
                                                         const int* __restrict__ bhs,
                                                         unsigned int* __restrict__ eb, int e,
                                                         int nbuck, int ce) {
    extern __shared__ int cur[];  // nbuck
    int b = blockIdx.x, t = threadIdx.x;
    for (int i = t; i < nbuck; i += 256) cur[i] = bhs[i * NCHUNKS + b];
    __syncthreads();
    int lo = b * ce, hi = min(lo + ce, e);
    for (int i = lo + t; i < hi; i += 256) {
        int s = src[i], d = dst[i];
        int pos = atomicAdd(&cur[d >> BUCKET_SHIFT], 1);
        eb[pos] = ((unsigned int)(d & (BUCKET_SZ - 1)) << 23) | (unsigned int)s;
    }
}

// Pass D: one block per bucket; LDS cursors; csr region is block-exclusive.

__global__ __launch_bounds__(256) void kD_fill(const unsigned int* __restrict__ eb,
                                               const int* __restrict__ bhs,
                                               const int* __restrict__ rowstart,
                                               int* __restrict__ csr_src,
                                               int n, int nbuck, int e) {
    __shared__ int cur[BUCKET_SZ];
    int k = blockIdx.x, t = threadIdx.x;
    int node0 = k << BUCKET_SHIFT;
    for (int i = t; i < BUCKET_SZ; i += 256) {
        int node = node0 + i;
        cur[i] = (node < n) ? rowstart[node] : 0;
    }
    __syncthreads();
    int lo = bhs[k * NCHUNKS];
    int hi = (k + 1 < nbuck) ? bhs[(k + 1) * NCHUNKS] : e;
    for (int i = lo + t; i < hi; i += 256) {
        unsigned int p = eb[i];
        int dl = (int)(p >> 23);
        int s = (int)(p & 0x7fffffu);
        int pos = atomicAdd(&cur[dl], 1);
        csr_src[pos] = s;
    }
}

// ---------------- prescale: xs[i][c] = x[i][c] * dinv[i]  (fp16) ----------------

__global__ __launch_bounds__(256) void k_prescale16(const float* __restrict__ x,
                                                    const float* __restrict__ dinv,
                                                    __half* __restrict__ xs, int n) {
    long long idx = (long long)blockIdx.x * 256 + threadIdx.x;
    if (idx < (long long)n * 16) {
        int row = (int)(idx >> 4);
        xs[idx] = __float2half(x[idx] * dinv[row]);
    }
}

// ---------------- gather in 16-dim input space: agg = dn * sum(xs) ----------------
// 1 wave per node; 4 edge-slots of 16 lanes; 2-way unroll per slot.

__global__ __launch_bounds__(256) void k_gather16(const int* __restrict__ rowstart,
                                                  const int* __restrict__ degi,
                                                  const int* __restrict__ csr_src,
                                                  const float* __restrict__ dinv,
                                                  const __half* __restrict__ xs,
                                                  float* __restrict__ out, int n) {
    int t = threadIdx.x;
    int node = blockIdx.x * 4 + (t >> 6);
    if (node >= n) return;
    int lane = t & 63;
    int c = lane & 15;
    int slot = lane >> 4;  // 0..3
    const int* sp = csr_src + rowstart[node];
    int deg = degi[node];
    float e0 = 0.f, e1 = 0.f;
    int k = slot;
    for (; k + 4 < deg; k += 8) {
        int s0 = sp[k], s1 = sp[k + 4];
        e0 += __half2float(xs[(size_t)s0 * 16 + c]);
        e1 += __half2float(xs[(size_t)s1 * 16 + c]);
    }
    if (k < deg) {
        int s0 = sp[k];
        e0 += __half2float(xs[(size_t)s0 * 16 + c]);
    }
    float acc = e0 + e1;
    acc += __shfl_xor(acc, 16);
    acc += __shfl_xor(acc, 32);
    if (slot == 0) {
        float dn = dinv[node];
        out[(size_t)node * 16 + c] = dn * (acc + __half2float(xs[(size_t)node * 16 + c]));
    }
}

// ---------------- fused MLP: h2s = (relu(agg@W1 + b1) @ W3) * dinv  (fp16) ----------------

__global__ __launch_bounds__(256) void k_mlp(const float* __restrict__ agg,
                                             const float* __restrict__ W1,
                                             const float* __restrict__ b1,
                                             const float* __restrict__ W3,
                                             const float* __restrict__ dinv,
                                             __half* __restrict__ h2s, int n) {
    __shared__ float w1[16 * 64];
    __shared__ float w3[64 * 32];
    __shared__ float bs[64];
    __shared__ float a[16 * 16];
    __shared__ float z[16 * 64];
    int t = threadIdx.x;
    for (int i = t; i < 16 * 64; i += 256) w1[i] = W1[i];
    for (int i = t; i < 64 * 32; i += 256) w3[i] = W3[i];
    if (t < 64) bs[t] = b1[t];
    int row0 = blockIdx.x * 16;
    {
        int r = t >> 4, c = t & 15;
        int row = row0 + r;
        a[t] = (row < n) ? agg[(size_t)row * 16 + c] : 0.f;
    }
    __syncthreads();
    for (int i = t; i < 1024; i += 256) {
        int r = i >> 6, c = i & 63;
        float acc = bs[c];
#pragma unroll
        for (int k = 0; k < 16; ++k) acc += a[r * 16 + k] * w1[k * 64 + c];
        z[i] = acc > 0.f ? acc : 0.f;
    }
    __syncthreads();
    for (int i = t; i < 512; i += 256) {
        int r = i >> 5, c = i & 31;
        float acc = 0.f;
#pragma unroll
        for (int k = 0; k < 64; ++k) acc += z[r * 64 + k] * w3[k * 32 + c];
        int row = row0 + r;
        if (row < n) h2s[(size_t)row * 32 + c] = __float2half(acc * dinv[row]);
    }
}

// ---------------- gather 32 feats + bias + relu + stats ----------------
// 1 wave per node; 2 edge-slots of 32 lanes; 2-way unroll per slot.

__global__ __launch_bounds__(256) void k_gather32_stats(const int* __restrict__ rowstart,
                                                        const int* __restrict__ degi,
                                                        const int* __restrict__ csr_src,
                                                        const float* __restrict__ dinv,
                                                        const __half* __restrict__ h2s,
                                                        const float* __restrict__ b3,
                                                        float* __restrict__ out,
                                                        float* __restrict__ partial, int n) {
    int t = threadIdx.x;
    int lane = t & 63;
    int c = lane & 31;
    int half = lane >> 5;
    float bias = b3[c];
    float s_sum = 0.f, s_sq = 0.f;
    for (int it = 0; it < 8; ++it) {
        int node = blockIdx.x * 32 + it * 4 + (t >> 6);
        if (node < n) {
            const int* sp = csr_src + rowstart[node];
            int deg = degi[node];
            float e0 = 0.f, e1 = 0.f;
            int k = half;
            for (; k + 2 < deg; k += 4) {
                int s0 = sp[k], s1 = sp[k + 2];
                e0 += __half2float(h2s[(size_t)s0 * 32 + c]);
                e1 += __half2float(h2s[(size_t)s1 * 32 + c]);
            }
            if (k < deg) {
                int s0 = sp[k];
                e0 += __half2float(h2s[(size_t)s0 * 32 + c]);
            }
            float acc = e0 + e1;
            acc += __shfl_xor(acc, 32);
            if (half == 0) {
                float dn = dinv[node];
                float v = dn * (acc + __half2float(h2s[(size_t)node * 32 + c])) + bias;
                v = v > 0.f ? v : 0.f;
                out[(size_t)node * 32 + c] = v;
                s_sum += v;
                s_sq += v * v;
            }
        }
    }
    __shared__ float ls[256], lq[256];
    ls[t] = s_sum;
    lq[t] = s_sq;
    __syncthreads();
    if (t < 32) {
        float a = 0.f, b = 0.f;
#pragma unroll
        for (int wv = 0; wv < 4; ++wv) {
            a += ls[wv * 64 + t];
            b += lq[wv * 64 + t];
        }
        atomicAdd(&partial[t], a);
        atomicAdd(&partial[32 + t], b);
    }
}

// ---------------- normalizer ----------------

__global__ void k_zero_partials(float* __restrict__ p) {
    int t = threadIdx.x;
    if (t < 64) p[t] = 0.f;
}

__global__ void k_finalize(const float* __restrict__ partial, float* __restrict__ meaninv, int n) {
    int t = threadIdx.x;
    if (t < 32) {
        float invn = 1.0f / (float)n;
        float mean = partial[t] * invn;
        float var = partial[32 + t] * invn - mean * mean;
        var = var > EPS ? var : EPS;
        meaninv[t] = mean;
        meaninv[32 + t] = rsqrtf(var);
    }
}

__global__ void k_norm(float* __restrict__ h, const float* __restrict__ meaninv, int n) {
    long long idx = (long long)blockIdx.x * blockDim.x + threadIdx.x;
    if (idx < (long long)n * 32) {
        int c = (int)(idx & 31);
        h[idx] = (h[idx] - meaninv[c]) * meaninv[32 + c];
    }
}

extern "C" void kernel_launch(void* const* d_in, const int* in_sizes, int n_in,
                              void* d_out, int out_size, void* d_ws, size_t ws_size,
                              hipStream_t stream) {
    const float* x  = (const float*)d_in[0];
    const int* ei   = (const int*)d_in[1];
    const float* W1 = (const float*)d_in[2];
    const float* b1 = (const float*)d_in[3];
    const float* W3 = (const float*)d_in[4];
    const float* b3 = (const float*)d_in[5];

    const int N = in_sizes[0] / 16;
    const int E = in_sizes[1] / 2;
    const int* src = ei;       // edge_index[0]
    const int* dst = ei + E;   // edge_index[1]

    const int NBUCK = (N + BUCKET_SZ - 1) >> BUCKET_SHIFT;  // 196 for N=100000
    const int CE = (E + NCHUNKS - 1) / NCHUNKS;
    const int BH_TOTAL = NBUCK * NCHUNKS;

    char* ws = (char*)d_ws;
    int*   degi     = (int*)ws;          ws += (size_t)N * 4;
    float* dinv     = (float*)ws;        ws += (size_t)N * 4;
    int*   rowstart = (int*)ws;          ws += (size_t)N * 4;
    int*   bsum     = (int*)ws;          ws += (size_t)SCAN_BS * 4;
    int*   bsum2    = (int*)ws;          ws += (size_t)SCAN_BS * 4;
    int*   bh       = (int*)ws;          ws += (size_t)BH_TOTAL * 4;
    int*   bhs      = (int*)ws;          ws += (size_t)BH_TOTAL * 4;
    unsigned int* eb = (unsigned int*)ws; ws += (size_t)E * 4;
    int*   csr_src  = (int*)ws;          ws += (size_t)E * 4;
    __half* xs      = (__half*)ws;       ws += (size_t)N * 16 * 2;
    __half* h2s     = (__half*)ws;       ws += (size_t)N * 32 * 2;
    float* aggX     = (float*)ws;        ws += (size_t)N * 16 * 4;
    float* partial  = (float*)ws;        ws += 64 * 4;
    float* meaninv  = (float*)ws;

    float* out = (float*)d_out;  // N*32

    const int NB = (N + SCAN_BS - 1) / SCAN_BS;
    const int NB2 = (BH_TOTAL + SCAN_BS - 1) / SCAN_BS;

    // degrees + rowstart
    k_zero_int<<<(N + 255) / 256, 256, 0, stream>>>(degi, N);
    k_hist<<<(E + 255) / 256, 256, 0, stream>>>(dst, degi, E);
    k_dinv<<<(N + 255) / 256, 256, 0, stream>>>(degi, dinv, N);
    k_scan_block<<<NB, SCAN_BS, 0, stream>>>(degi, rowstart, bsum, N);
    k_scan_tops<<<1, SCAN_BS, 0, stream>>>(bsum, NB);
    k_scan_add<<<NB, SCAN_BS, 0, stream>>>(rowstart, bsum, N);

    // bucketed edge sort + csr fill
    kA_bucket_hist<<<NCHUNKS, 256, NBUCK * 4, stream>>>(dst, bh, E, NBUCK, CE);
    k_scan_block<<<NB2, SCAN_BS, 0, stream>>>(bh, bhs, bsum2, BH_TOTAL);
    k_scan_tops<<<1, SCAN_BS, 0, stream>>>(bsum2, NB2);
    k_scan_add<<<NB2, SCAN_BS, 0, stream>>>(bhs, bsum2, BH_TOTAL);
    kC_bucket_scatter<<<NCHUNKS, 256, NBUCK * 4, stream>>>(src, dst, bhs, eb, E, NBUCK, CE);
    kD_fill<<<NBUCK, 256, 0, stream>>>(eb, bhs, rowstart, csr_src, N, NBUCK, E);

    // layer 1: prescale x by dinv (fp16), gather in 16-dim space, fused MLP
    k_prescale16<<<((long long)N * 16 + 255) / 256, 256, 0, stream>>>(x, dinv, xs, N);
    k_gather16<<<(N + 3) / 4, 256, 0, stream>>>(rowstart, degi, csr_src, dinv, xs, aggX, N);
    k_mlp<<<(N + 15) / 16, 256, 0, stream>>>(aggX, W1, b1, W3, dinv, h2s, N);

    // layer 2 aggregation + bias + relu + stats
    k_zero_partials<<<1, 64, 0, stream>>>(partial);
    k_gather32_stats<<<(N + 31) / 32, 256, 0, stream>>>(rowstart, degi, csr_src, dinv, h2s,
                                                        b3, out, partial, N);

    // normalizer
    k_finalize<<<1, 64, 0, stream>>>(partial, meaninv, N);
    k_norm<<<((long long)N * 32 + 255) / 256, 256, 0, stream>>>(out, meaninv, N);
}

// Round 6
// 198.064 us; speedup vs baseline: 3.6327x; 1.4600x over previous
//
#include <hip/hip_runtime.h>
#include <hip/hip_fp16.h>

#define EPS 0.01f
#define SCAN_BS 512
#define NCHUNKS 256
#define BUCKET_SHIFT 9
#define BUCKET_SZ (1 << BUCKET_SHIFT)

// ---------------- exclusive scan (3-kernel, n <= 512*512) ----------------

__global__ __launch_bounds__(SCAN_BS) void k_scan_block(const int* __restrict__ in,
                                                        int* __restrict__ out,
                                                        int* __restrict__ bsum, int n) {
    __shared__ int sd[SCAN_BS];
    int t = threadIdx.x;
    int gid = blockIdx.x * SCAN_BS + t;
    int v = (gid < n) ? in[gid] : 0;
    sd[t] = v;
    __syncthreads();
    for (int off = 1; off < SCAN_BS; off <<= 1) {
        int x = (t >= off) ? sd[t - off] : 0;
        __syncthreads();
        sd[t] += x;
        __syncthreads();
    }
    if (gid < n) out[gid] = sd[t] - v;  // exclusive
    if (t == SCAN_BS - 1) bsum[blockIdx.x] = sd[t];
}

__global__ __launch_bounds__(SCAN_BS) void k_scan_tops(int* __restrict__ bsum, int nb) {
    __shared__ int sd[SCAN_BS];
    int t = threadIdx.x;
    int v = (t < nb) ? bsum[t] : 0;
    sd[t] = v;
    __syncthreads();
    for (int off = 1; off < SCAN_BS; off <<= 1) {
        int x = (t >= off) ? sd[t - off] : 0;
        __syncthreads();
        sd[t] += x;
        __syncthreads();
    }
    if (t < nb) bsum[t] = sd[t] - v;  // exclusive
}

__global__ __launch_bounds__(SCAN_BS) void k_scan_add(int* __restrict__ out,
                                                      const int* __restrict__ bsum, int n) {
    int gid = blockIdx.x * SCAN_BS + threadIdx.x;
    if (gid < n) out[gid] += bsum[blockIdx.x];
}

// ---------------- bucketed edge sort ----------------

__global__ __launch_bounds__(256) void kA_bucket_hist(const int* __restrict__ dst,
                                                      int* __restrict__ bh, int e,
                                                      int nbuck, int ce) {
    extern __shared__ int hist[];  // nbuck
    int b = blockIdx.x, t = threadIdx.x;
    for (int i = t; i < nbuck; i += 256) hist[i] = 0;
    __syncthreads();
    int lo = b * ce, hi = min(lo + ce, e);
    for (int i = lo + t; i < hi; i += 256) atomicAdd(&hist[dst[i] >> BUCKET_SHIFT], 1);
    __syncthreads();
    for (int i = t; i < nbuck; i += 256) bh[i * NCHUNKS + b] = hist[i];  // [bucket][chunk]
}

__global__ __launch_bounds__(256) void kC_bucket_scatter(const int* __restrict__ src,
                                                         const int* __restrict__ dst,
                                                         const int* __restrict__ bhs,
                                                         unsigned int* __restrict__ eb, int e,
                                                         int nbuck, int ce) {
    extern __shared__ int cur[];  // nbuck
    int b = blockIdx.x, t = threadIdx.x;
    for (int i = t; i < nbuck; i += 256) cur[i] = bhs[i * NCHUNKS + b];
    __syncthreads();
    int lo = b * ce, hi = min(lo + ce, e);
    for (int i = lo + t; i < hi; i += 256) {
        int s = src[i], d = dst[i];
        int pos = atomicAdd(&cur[d >> BUCKET_SHIFT], 1);
        eb[pos] = ((unsigned int)(d & (BUCKET_SZ - 1)) << 23) | (unsigned int)s;
    }
}

// degi from the bucket-sorted edge records (replaces 1.6M global atomics)
__global__ __launch_bounds__(256) void kDeg(const unsigned int* __restrict__ eb,
                                            const int* __restrict__ bhs,
                                            int* __restrict__ degi,
                                            int n, int nbuck, int e) {
    __shared__ int hist[BUCKET_SZ];
    int k = blockIdx.x, t = threadIdx.x;
    for (int i = t; i < BUCKET_SZ; i += 256) hist[i] = 0;
    __syncthreads();
    int lo = bhs[k * NCHUNKS];
    int hi = (k + 1 < nbuck) ? bhs[(k + 1) * NCHUNKS] : e;
    for (int i = lo + t; i < hi; i += 256) atomicAdd(&hist[eb[i] >> 23], 1);
    __syncthreads();
    int node0 = k << BUCKET_SHIFT;
    for (int i = t; i < BUCKET_SZ; i += 256) {
        int node = node0 + i;
        if (node < n) degi[node] = hist[i];
    }
}

__global__ void k_dinv(const int* __restrict__ degi, float* __restrict__ dinv, int n) {
    int i = blockIdx.x * blockDim.x + threadIdx.x;
    if (i < n) dinv[i] = rsqrtf((float)degi[i] + 1.0f);  // +1 self-loop
}

__global__ __launch_bounds__(256) void kD_fill(const unsigned int* __restrict__ eb,
                                               const int* __restrict__ bhs,
                                               const int* __restrict__ rowstart,
                                               int* __restrict__ csr_src,
                                               int n, int nbuck, int e) {
    __shared__ int cur[BUCKET_SZ];
    int k = blockIdx.x, t = threadIdx.x;
    int node0 = k << BUCKET_SHIFT;
    for (int i = t; i < BUCKET_SZ; i += 256) {
        int node = node0 + i;
        cur[i] = (node < n) ? rowstart[node] : 0;
    }
    __syncthreads();
    int lo = bhs[k * NCHUNKS];
    int hi = (k + 1 < nbuck) ? bhs[(k + 1) * NCHUNKS] : e;
    for (int i = lo + t; i < hi; i += 256) {
        unsigned int p = eb[i];
        int dl = (int)(p >> 23);
        int s = (int)(p & 0x7fffffu);
        int pos = atomicAdd(&cur[dl], 1);
        csr_src[pos] = s;
    }
}

// ---------------- prescale: xs[i][c] = x[i][c] * dinv[i]  (fp16) ----------------

__global__ __launch_bounds__(256) void k_prescale16(const float* __restrict__ x,
                                                    const float* __restrict__ dinv,
                                                    __half* __restrict__ xs, int n) {
    long long idx = (long long)blockIdx.x * 256 + threadIdx.x;
    if (idx < (long long)n * 16) {
        int row = (int)(idx >> 4);
        xs[idx] = __float2half(x[idx] * dinv[row]);
    }
}

// ---------------- fused layer 1: gather16 (half2, 8 slots) + MLP ----------------
// block = 256 threads = 4 waves; 16 nodes per block (4 per wave).

__global__ __launch_bounds__(256) void k_l1_fused(const int* __restrict__ rowstart,
                                                  const int* __restrict__ degi,
                                                  const int* __restrict__ csr_src,
                                                  const float* __restrict__ dinv,
                                                  const __half* __restrict__ xs,
                                                  const float* __restrict__ W1,
                                                  const float* __restrict__ b1,
                                                  const float* __restrict__ W3,
                                                  __half* __restrict__ h2s, int n) {
    __shared__ float w1[16 * 64];
    __shared__ float w3[64 * 32];
    __shared__ float bs[64];
    __shared__ __align__(16) float a[16 * 16];
    __shared__ float z[16 * 64];
    int t = threadIdx.x;
    for (int i = t; i < 16 * 64; i += 256) w1[i] = W1[i];
    for (int i = t; i < 64 * 32; i += 256) w3[i] = W3[i];
    if (t < 64) bs[t] = b1[t];

    int row0 = blockIdx.x * 16;
    int wv = t >> 6;
    int lane = t & 63;
    int c2 = lane & 7;        // half2 column pair (cols 2c2, 2c2+1)
    int slot = lane >> 3;     // 0..7 edge slots
    const __half2* xs2 = (const __half2*)xs;

    // phase 1: gather 4 nodes per wave
    for (int nid = 0; nid < 4; ++nid) {
        int node = row0 + wv * 4 + nid;
        if (node < n) {
            const int* sp = csr_src + rowstart[node];
            int deg = degi[node];
            float ax = 0.f, ay = 0.f, bx = 0.f, by = 0.f;
            int k = slot;
            for (; k + 8 < deg; k += 16) {
                int s0 = sp[k], s1 = sp[k + 8];
                float2 v0 = __half22float2(xs2[(size_t)s0 * 8 + c2]);
                float2 v1 = __half22float2(xs2[(size_t)s1 * 8 + c2]);
                ax += v0.x; ay += v0.y;
                bx += v1.x; by += v1.y;
            }
            if (k < deg) {
                int s0 = sp[k];
                float2 v0 = __half22float2(xs2[(size_t)s0 * 8 + c2]);
                ax += v0.x; ay += v0.y;
            }
            float sx = ax + bx, sy = ay + by;
            sx += __shfl_xor(sx, 8);  sy += __shfl_xor(sy, 8);
            sx += __shfl_xor(sx, 16); sy += __shfl_xor(sy, 16);
            sx += __shfl_xor(sx, 32); sy += __shfl_xor(sy, 32);
            if (slot == 0) {
                float2 self = __half22float2(xs2[(size_t)node * 8 + c2]);
                float dn = dinv[node];
                int r = wv * 4 + nid;
                ((float2*)(a + r * 16))[c2] = make_float2(dn * (sx + self.x), dn * (sy + self.y));
            }
        }
    }
    __syncthreads();

    // phase 2: z = relu(a @ W1 + b1)
    for (int i = t; i < 1024; i += 256) {
        int r = i >> 6, c = i & 63;
        float acc = bs[c];
#pragma unroll
        for (int k = 0; k < 16; ++k) acc += a[r * 16 + k] * w1[k * 64 + c];
        z[i] = acc > 0.f ? acc : 0.f;
    }
    __syncthreads();
    // h2s = (z @ W3) * dinv  (fp16)
    for (int i = t; i < 512; i += 256) {
        int r = i >> 5, c = i & 31;
        float acc = 0.f;
#pragma unroll
        for (int k = 0; k < 64; ++k) acc += z[r * 64 + k] * w3[k * 32 + c];
        int row = row0 + r;
        if (row < n) h2s[(size_t)row * 32 + c] = __float2half(acc * dinv[row]);
    }
}

// ---------------- gather 32 feats (half2, 4 slots) + bias + relu + stats ----------------
// 1 wave per node-iter; 16 col-pairs x 4 edge-slots; 2-way unroll per slot.

__global__ __launch_bounds__(256) void k_gather32_stats(const int* __restrict__ rowstart,
                                                        const int* __restrict__ degi,
                                                        const int* __restrict__ csr_src,
                                                        const float* __restrict__ dinv,
                                                        const __half* __restrict__ h2s,
                                                        const float* __restrict__ b3,
                                                        float* __restrict__ out,
                                                        float* __restrict__ partial, int n) {
    int t = threadIdx.x;
    int lane = t & 63;
    int c2 = lane & 15;       // cols 2c2, 2c2+1
    int slot = lane >> 4;     // 0..3
    const __half2* h2 = (const __half2*)h2s;
    float2 bias = ((const float2*)b3)[c2];
    float s_x = 0.f, s_y = 0.f, q_x = 0.f, q_y = 0.f;
    for (int it = 0; it < 8; ++it) {
        int node = blockIdx.x * 32 + it * 4 + (t >> 6);
        if (node < n) {
            const int* sp = csr_src + rowstart[node];
            int deg = degi[node];
            float ax = 0.f, ay = 0.f, bx = 0.f, by = 0.f;
            int k = slot;
            for (; k + 4 < deg; k += 8) {
                int s0 = sp[k], s1 = sp[k + 4];
                float2 v0 = __half22float2(h2[(size_t)s0 * 16 + c2]);
                float2 v1 = __half22float2(h2[(size_t)s1 * 16 + c2]);
                ax += v0.x; ay += v0.y;
                bx += v1.x; by += v1.y;
            }
            if (k < deg) {
                int s0 = sp[k];
                float2 v0 = __half22float2(h2[(size_t)s0 * 16 + c2]);
                ax += v0.x; ay += v0.y;
            }
            float sx = ax + bx, sy = ay + by;
            sx += __shfl_xor(sx, 16); sy += __shfl_xor(sy, 16);
            sx += __shfl_xor(sx, 32); sy += __shfl_xor(sy, 32);
            if (slot == 0) {
                float2 self = __half22float2(h2[(size_t)node * 16 + c2]);
                float dn = dinv[node];
                float vx = dn * (sx + self.x) + bias.x;
                float vy = dn * (sy + self.y) + bias.y;
                vx = vx > 0.f ? vx : 0.f;
                vy = vy > 0.f ? vy : 0.f;
                ((float2*)(out + (size_t)node * 32))[c2] = make_float2(vx, vy);
                s_x += vx; s_y += vy;
                q_x += vx * vx; q_y += vy * vy;
            }
        }
    }
    __shared__ float ls[128], lq[128];
    int wv = t >> 6;
    if ((t & 63) < 16) {
        ls[wv * 32 + 2 * c2] = s_x;
        ls[wv * 32 + 2 * c2 + 1] = s_y;
        lq[wv * 32 + 2 * c2] = q_x;
        lq[wv * 32 + 2 * c2 + 1] = q_y;
    }
    __syncthreads();
    if (t < 32) {
        float a = 0.f, b = 0.f;
#pragma unroll
        for (int w = 0; w < 4; ++w) {
            a += ls[w * 32 + t];
            b += lq[w * 32 + t];
        }
        atomicAdd(&partial[t], a);
        atomicAdd(&partial[32 + t], b);
    }
}

// ---------------- normalizer ----------------

__global__ void k_zero_partials(float* __restrict__ p) {
    int t = threadIdx.x;
    if (t < 64) p[t] = 0.f;
}

__global__ void k_finalize(const float* __restrict__ partial, float* __restrict__ meaninv, int n) {
    int t = threadIdx.x;
    if (t < 32) {
        float invn = 1.0f / (float)n;
        float mean = partial[t] * invn;
        float var = partial[32 + t] * invn - mean * mean;
        var = var > EPS ? var : EPS;
        meaninv[t] = mean;
        meaninv[32 + t] = rsqrtf(var);
    }
}

__global__ void k_norm(float* __restrict__ h, const float* __restrict__ meaninv, int n) {
    long long idx = (long long)blockIdx.x * blockDim.x + threadIdx.x;
    if (idx < (long long)n * 32) {
        int c = (int)(idx & 31);
        h[idx] = (h[idx] - meaninv[c]) * meaninv[32 + c];
    }
}

extern "C" void kernel_launch(void* const* d_in, const int* in_sizes, int n_in,
                              void* d_out, int out_size, void* d_ws, size_t ws_size,
                              hipStream_t stream) {
    const float* x  = (const float*)d_in[0];
    const int* ei   = (const int*)d_in[1];
    const float* W1 = (const float*)d_in[2];
    const float* b1 = (const float*)d_in[3];
    const float* W3 = (const float*)d_in[4];
    const float* b3 = (const float*)d_in[5];

    const int N = in_sizes[0] / 16;
    const int E = in_sizes[1] / 2;
    const int* src = ei;       // edge_index[0]
    const int* dst = ei + E;   // edge_index[1]

    const int NBUCK = (N + BUCKET_SZ - 1) >> BUCKET_SHIFT;  // 196 for N=100000
    const int CE = (E + NCHUNKS - 1) / NCHUNKS;
    const int BH_TOTAL = NBUCK * NCHUNKS;

    char* ws = (char*)d_ws;
    int*   degi     = (int*)ws;          ws += (size_t)N * 4;
    float* dinv     = (float*)ws;        ws += (size_t)N * 4;
    int*   rowstart = (int*)ws;          ws += (size_t)N * 4;
    int*   bsum     = (int*)ws;          ws += (size_t)SCAN_BS * 4;
    int*   bsum2    = (int*)ws;          ws += (size_t)SCAN_BS * 4;
    int*   bh       = (int*)ws;          ws += (size_t)BH_TOTAL * 4;
    int*   bhs      = (int*)ws;          ws += (size_t)BH_TOTAL * 4;
    unsigned int* eb = (unsigned int*)ws; ws += (size_t)E * 4;
    int*   csr_src  = (int*)ws;          ws += (size_t)E * 4;
    __half* xs      = (__half*)ws;       ws += (size_t)N * 16 * 2;
    __half* h2s     = (__half*)ws;       ws += (size_t)N * 32 * 2;
    float* partial  = (float*)ws;        ws += 64 * 4;
    float* meaninv  = (float*)ws;

    float* out = (float*)d_out;  // N*32

    const int NB = (N + SCAN_BS - 1) / SCAN_BS;
    const int NB2 = (BH_TOTAL + SCAN_BS - 1) / SCAN_BS;

    // bucketed edge sort
    kA_bucket_hist<<<NCHUNKS, 256, NBUCK * 4, stream>>>(dst, bh, E, NBUCK, CE);
    k_scan_block<<<NB2, SCAN_BS, 0, stream>>>(bh, bhs, bsum2, BH_TOTAL);
    k_scan_tops<<<1, SCAN_BS, 0, stream>>>(bsum2, NB2);
    k_scan_add<<<NB2, SCAN_BS, 0, stream>>>(bhs, bsum2, BH_TOTAL);
    kC_bucket_scatter<<<NCHUNKS, 256, NBUCK * 4, stream>>>(src, dst, bhs, eb, E, NBUCK, CE);

    // degrees from sorted records, dinv, rowstart, csr fill
    kDeg<<<NBUCK, 256, 0, stream>>>(eb, bhs, degi, N, NBUCK, E);
    k_dinv<<<(N + 255) / 256, 256, 0, stream>>>(degi, dinv, N);
    k_scan_block<<<NB, SCAN_BS, 0, stream>>>(degi, rowstart, bsum, N);
    k_scan_tops<<<1, SCAN_BS, 0, stream>>>(bsum, NB);
    k_scan_add<<<NB, SCAN_BS, 0, stream>>>(rowstart, bsum, N);
    kD_fill<<<NBUCK, 256, 0, stream>>>(eb, bhs, rowstart, csr_src, N, NBUCK, E);

    // layer 1: prescale + fused gather/MLP
    k_prescale16<<<((long long)N * 16 + 255) / 256, 256, 0, stream>>>(x, dinv, xs, N);
    k_l1_fused<<<(N + 15) / 16, 256, 0, stream>>>(rowstart, degi, csr_src, dinv, xs,
                                                  W1, b1, W3, h2s, N);

    // layer 2 aggregation + bias + relu + stats
    k_zero_partials<<<1, 64, 0, stream>>>(partial);
    k_gather32_stats<<<(N + 31) / 32, 256, 0, stream>>>(rowstart, degi, csr_src, dinv, h2s,
                                                        b3, out, partial, N);

    // normalizer
    k_finalize<<<1, 64, 0, stream>>>(partial, meaninv, N);
    k_norm<<<((long long)N * 32 + 255) / 256, 256, 0, stream>>>(out, meaninv, N);
}

// Round 7
// 194.558 us; speedup vs baseline: 3.6981x; 1.0180x over previous
//
#include <hip/hip_runtime.h>
#include <hip/hip_fp16.h>

#define EPS 0.01f
#define SCAN_BS 512
#define NCHUNKS 256
#define BUCKET_SHIFT 9
#define BUCKET_SZ (1 << BUCKET_SHIFT)

// ---------------- exclusive scan (3-kernel, n <= 512*512) ----------------

__global__ __launch_bounds__(SCAN_BS) void k_scan_block(const int* __restrict__ in,
                                                        int* __restrict__ out,
                                                        int* __restrict__ bsum, int n) {
    __shared__ int sd[SCAN_BS];
    int t = threadIdx.x;
    int gid = blockIdx.x * SCAN_BS + t;
    int v = (gid < n) ? in[gid] : 0;
    sd[t] = v;
    __syncthreads();
    for (int off = 1; off < SCAN_BS; off <<= 1) {
        int x = (t >= off) ? sd[t - off] : 0;
        __syncthreads();
        sd[t] += x;
        __syncthreads();
    }
    if (gid < n) out[gid] = sd[t] - v;  // exclusive
    if (t == SCAN_BS - 1) bsum[blockIdx.x] = sd[t];
}

__global__ __launch_bounds__(SCAN_BS) void k_scan_tops(int* __restrict__ bsum, int nb) {
    __shared__ int sd[SCAN_BS];
    int t = threadIdx.x;
    int v = (t < nb) ? bsum[t] : 0;
    sd[t] = v;
    __syncthreads();
    for (int off = 1; off < SCAN_BS; off <<= 1) {
        int x = (t >= off) ? sd[t - off] : 0;
        __syncthreads();
        sd[t] += x;
        __syncthreads();
    }
    if (t < nb) bsum[t] = sd[t] - v;  // exclusive
}

__global__ __launch_bounds__(SCAN_BS) void k_scan_add(int* __restrict__ out,
                                                      const int* __restrict__ bsum, int n) {
    int gid = blockIdx.x * SCAN_BS + threadIdx.x;
    if (gid < n) out[gid] += bsum[blockIdx.x];
}

// ---------------- bucketed edge sort ----------------

__global__ __launch_bounds__(256) void kA_bucket_hist(const int* __restrict__ dst,
                                                      int* __restrict__ bh, int e,
                                                      int nbuck, int ce) {
    extern __shared__ int hist[];  // nbuck
    int b = blockIdx.x, t = threadIdx.x;
    for (int i = t; i < nbuck; i += 256) hist[i] = 0;
    __syncthreads();
    int lo = b * ce, hi = min(lo + ce, e);
    for (int i = lo + t; i < hi; i += 256) atomicAdd(&hist[dst[i] >> BUCKET_SHIFT], 1);
    __syncthreads();
    for (int i = t; i < nbuck; i += 256) bh[i * NCHUNKS + b] = hist[i];  // [bucket][chunk]
}

__global__ __launch_bounds__(256) void kC_bucket_scatter(const int* __restrict__ src,
                                                         const int* __restrict__ dst,
                                                         const int* __restrict__ bhs,
                                                         unsigned int* __restrict__ eb, int e,
                                                         int nbuck, int ce) {
    extern __shared__ int cur[];  // nbuck
    int b = blockIdx.x, t = threadIdx.x;
    for (int i = t; i < nbuck; i += 256) cur[i] = bhs[i * NCHUNKS + b];
    __syncthreads();
    int lo = b * ce, hi = min(lo + ce, e);
    for (int i = lo + t; i < hi; i += 256) {
        int s = src[i], d = dst[i];
        int pos = atomicAdd(&cur[d >> BUCKET_SHIFT], 1);
        eb[pos] = ((unsigned int)(d & (BUCKET_SZ - 1)) << 23) | (unsigned int)s;
    }
}

// Fused: per-bucket degree hist -> block scan -> rowstart/degi/dinv, plus
// xs = x*dinv prescale (fp16) and partial-zero (block 0).
__global__ __launch_bounds__(256) void kDeg_scan_prescale(const unsigned int* __restrict__ eb,
                                                          const int* __restrict__ bhs,
                                                          const float* __restrict__ x,
                                                          int* __restrict__ degi,
                                                          float* __restrict__ dinv,
                                                          int* __restrict__ rowstart,
                                                          __half* __restrict__ xs,
                                                          float* __restrict__ partial,
                                                          int n, int nbuck, int e) {
    __shared__ int hist[BUCKET_SZ];
    __shared__ int ps[256];
    __shared__ float dv[BUCKET_SZ];
    int k = blockIdx.x, t = threadIdx.x;
    if (k == 0 && t < 64) partial[t] = 0.f;
    for (int i = t; i < BUCKET_SZ; i += 256) hist[i] = 0;
    __syncthreads();
    int lo = bhs[k * NCHUNKS];
    int hi = (k + 1 < nbuck) ? bhs[(k + 1) * NCHUNKS] : e;
    for (int i = lo + t; i < hi; i += 256) atomicAdd(&hist[eb[i] >> 23], 1);
    __syncthreads();
    // block scan of 512 hist entries (2 per thread)
    int a0 = hist[2 * t], a1 = hist[2 * t + 1];
    ps[t] = a0 + a1;
    __syncthreads();
    for (int off = 1; off < 256; off <<= 1) {
        int v = (t >= off) ? ps[t - off] : 0;
        __syncthreads();
        ps[t] += v;
        __syncthreads();
    }
    int excl = ps[t] - (a0 + a1);
    int node0 = k << BUCKET_SHIFT;
    {
        int nd0 = node0 + 2 * t, nd1 = nd0 + 1;
        float d0 = rsqrtf((float)a0 + 1.0f);
        float d1 = rsqrtf((float)a1 + 1.0f);
        dv[2 * t] = d0;
        dv[2 * t + 1] = d1;
        if (nd0 < n) {
            degi[nd0] = a0;
            dinv[nd0] = d0;
            rowstart[nd0] = lo + excl;
        }
        if (nd1 < n) {
            degi[nd1] = a1;
            dinv[nd1] = d1;
            rowstart[nd1] = lo + excl + a0;
        }
    }
    __syncthreads();
    // prescale: xs[node][c] = x[node][c] * dinv[node]
    for (int i = t; i < BUCKET_SZ * 16; i += 256) {
        int rl = i >> 4;
        int node = node0 + rl;
        if (node < n) xs[(size_t)node * 16 + (i & 15)] = __float2half(x[(size_t)node * 16 + (i & 15)] * dv[rl]);
    }
}

__global__ __launch_bounds__(256) void kD_fill(const unsigned int* __restrict__ eb,
                                               const int* __restrict__ bhs,
                                               const int* __restrict__ rowstart,
                                               int* __restrict__ csr_src,
                                               int n, int nbuck, int e) {
    __shared__ int cur[BUCKET_SZ];
    int k = blockIdx.x, t = threadIdx.x;
    int node0 = k << BUCKET_SHIFT;
    for (int i = t; i < BUCKET_SZ; i += 256) {
        int node = node0 + i;
        cur[i] = (node < n) ? rowstart[node] : 0;
    }
    __syncthreads();
    int lo = bhs[k * NCHUNKS];
    int hi = (k + 1 < nbuck) ? bhs[(k + 1) * NCHUNKS] : e;
    for (int i = lo + t; i < hi; i += 256) {
        unsigned int p = eb[i];
        int dl = (int)(p >> 23);
        int s = (int)(p & 0x7fffffu);
        int pos = atomicAdd(&cur[dl], 1);
        csr_src[pos] = s;
    }
}

// ---------------- fused layer 1: gather16 (half2, 8 chunked slots) + MLP ----------------
// block = 256 threads = 4 waves; 16 nodes per block (4 per wave).

__global__ __launch_bounds__(256) void k_l1_fused(const int* __restrict__ rowstart,
                                                  const int* __restrict__ degi,
                                                  const int* __restrict__ csr_src,
                                                  const float* __restrict__ dinv,
                                                  const __half* __restrict__ xs,
                                                  const float* __restrict__ W1,
                                                  const float* __restrict__ b1,
                                                  const float* __restrict__ W3,
                                                  __half* __restrict__ h2s, int n) {
    __shared__ float w1[16 * 64];
    __shared__ float w3[64 * 32];
    __shared__ float bs[64];
    __shared__ __align__(16) float a[16 * 16];
    __shared__ float z[16 * 64];
    int t = threadIdx.x;
    for (int i = t; i < 16 * 64; i += 256) w1[i] = W1[i];
    for (int i = t; i < 64 * 32; i += 256) w3[i] = W3[i];
    if (t < 64) bs[t] = b1[t];

    int row0 = blockIdx.x * 16;
    int wv = t >> 6;
    int lane = t & 63;
    int c2 = lane & 7;        // half2 column pair (cols 2c2, 2c2+1)
    int slot = lane >> 3;     // 0..7 edge slots (contiguous chunks)
    const __half2* xs2 = (const __half2*)xs;

    for (int nid = 0; nid < 4; ++nid) {
        int node = row0 + wv * 4 + nid;
        if (node < n) {
            const int* sp = csr_src + rowstart[node];
            int deg = degi[node];
            int L = (deg + 7) >> 3;
            int base = slot * L;
            int end = min(base + L, deg);
            float ax = 0.f, ay = 0.f, bx = 0.f, by = 0.f;
            int k = base;
            for (; k + 2 <= end; k += 2) {
                int s0 = sp[k], s1 = sp[k + 1];
                float2 v0 = __half22float2(xs2[(size_t)s0 * 8 + c2]);
                float2 v1 = __half22float2(xs2[(size_t)s1 * 8 + c2]);
                ax += v0.x; ay += v0.y;
                bx += v1.x; by += v1.y;
            }
            if (k < end) {
                int s0 = sp[k];
                float2 v0 = __half22float2(xs2[(size_t)s0 * 8 + c2]);
                ax += v0.x; ay += v0.y;
            }
            float sx = ax + bx, sy = ay + by;
            sx += __shfl_xor(sx, 8);  sy += __shfl_xor(sy, 8);
            sx += __shfl_xor(sx, 16); sy += __shfl_xor(sy, 16);
            sx += __shfl_xor(sx, 32); sy += __shfl_xor(sy, 32);
            if (slot == 0) {
                float2 self = __half22float2(xs2[(size_t)node * 8 + c2]);
                float dn = dinv[node];
                int r = wv * 4 + nid;
                ((float2*)(a + r * 16))[c2] = make_float2(dn * (sx + self.x), dn * (sy + self.y));
            }
        }
    }
    __syncthreads();

    // z = relu(a @ W1 + b1)
    for (int i = t; i < 1024; i += 256) {
        int r = i >> 6, c = i & 63;
        float acc = bs[c];
#pragma unroll
        for (int k = 0; k < 16; ++k) acc += a[r * 16 + k] * w1[k * 64 + c];
        z[i] = acc > 0.f ? acc : 0.f;
    }
    __syncthreads();
    // h2s = (z @ W3) * dinv  (fp16)
    for (int i = t; i < 512; i += 256) {
        int r = i >> 5, c = i & 31;
        float acc = 0.f;
#pragma unroll
        for (int k = 0; k < 64; ++k) acc += z[r * 64 + k] * w3[k * 32 + c];
        int row = row0 + r;
        if (row < n) h2s[(size_t)row * 32 + c] = __float2half(acc * dinv[row]);
    }
}

// ---------------- gather 32 feats (half2, 4 chunked slots, 4-way unroll) ----------------

__global__ __launch_bounds__(256) void k_gather32_stats(const int* __restrict__ rowstart,
                                                        const int* __restrict__ degi,
                                                        const int* __restrict__ csr_src,
                                                        const float* __restrict__ dinv,
                                                        const __half* __restrict__ h2s,
                                                        const float* __restrict__ b3,
                                                        float* __restrict__ out,
                                                        float* __restrict__ partial, int n) {
    int t = threadIdx.x;
    int lane = t & 63;
    int c2 = lane & 15;       // cols 2c2, 2c2+1
    int slot = lane >> 4;     // 0..3 (contiguous chunks)
    const __half2* h2 = (const __half2*)h2s;
    float2 bias = ((const float2*)b3)[c2];
    float s_x = 0.f, s_y = 0.f, q_x = 0.f, q_y = 0.f;
    for (int it = 0; it < 8; ++it) {
        int node = blockIdx.x * 32 + it * 4 + (t >> 6);
        if (node < n) {
            const int* sp = csr_src + rowstart[node];
            int deg = degi[node];
            int L = (deg + 3) >> 2;
            int base = slot * L;
            int end = min(base + L, deg);
            float ax = 0.f, ay = 0.f, bx = 0.f, by = 0.f;
            float cx = 0.f, cy = 0.f, dx = 0.f, dy = 0.f;
            int k = base;
            for (; k + 4 <= end; k += 4) {
                int s0 = sp[k], s1 = sp[k + 1], s2 = sp[k + 2], s3 = sp[k + 3];
                float2 v0 = __half22float2(h2[(size_t)s0 * 16 + c2]);
                float2 v1 = __half22float2(h2[(size_t)s1 * 16 + c2]);
                float2 v2 = __half22float2(h2[(size_t)s2 * 16 + c2]);
                float2 v3 = __half22float2(h2[(size_t)s3 * 16 + c2]);
                ax += v0.x; ay += v0.y;
                bx += v1.x; by += v1.y;
                cx += v2.x; cy += v2.y;
                dx += v3.x; dy += v3.y;
            }
            for (; k < end; ++k) {
                int s0 = sp[k];
                float2 v0 = __half22float2(h2[(size_t)s0 * 16 + c2]);
                ax += v0.x; ay += v0.y;
            }
            float sx = (ax + bx) + (cx + dx);
            float sy = (ay + by) + (cy + dy);
            sx += __shfl_xor(sx, 16); sy += __shfl_xor(sy, 16);
            sx += __shfl_xor(sx, 32); sy += __shfl_xor(sy, 32);
            if (slot == 0) {
                float2 self = __half22float2(h2[(size_t)node * 16 + c2]);
                float dn = dinv[node];
                float vx = dn * (sx + self.x) + bias.x;
                float vy = dn * (sy + self.y) + bias.y;
                vx = vx > 0.f ? vx : 0.f;
                vy = vy > 0.f ? vy : 0.f;
                ((float2*)(out + (size_t)node * 32))[c2] = make_float2(vx, vy);
                s_x += vx; s_y += vy;
                q_x += vx * vx; q_y += vy * vy;
            }
        }
    }
    __shared__ float ls[128], lq[128];
    int wv = t >> 6;
    if ((t & 63) < 16) {
        ls[wv * 32 + 2 * c2] = s_x;
        ls[wv * 32 + 2 * c2 + 1] = s_y;
        lq[wv * 32 + 2 * c2] = q_x;
        lq[wv * 32 + 2 * c2 + 1] = q_y;
    }
    __syncthreads();
    if (t < 32) {
        float a = 0.f, b = 0.f;
#pragma unroll
        for (int w = 0; w < 4; ++w) {
            a += ls[w * 32 + t];
            b += lq[w * 32 + t];
        }
        atomicAdd(&partial[t], a);
        atomicAdd(&partial[32 + t], b);
    }
}

// ---------------- normalizer ----------------

__global__ void k_finalize(const float* __restrict__ partial, float* __restrict__ meaninv, int n) {
    int t = threadIdx.x;
    if (t < 32) {
        float invn = 1.0f / (float)n;
        float mean = partial[t] * invn;
        float var = partial[32 + t] * invn - mean * mean;
        var = var > EPS ? var : EPS;
        meaninv[t] = mean;
        meaninv[32 + t] = rsqrtf(var);
    }
}

__global__ void k_norm(float* __restrict__ h, const float* __restrict__ meaninv, int n) {
    long long idx = (long long)blockIdx.x * blockDim.x + threadIdx.x;
    if (idx < (long long)n * 32) {
        int c = (int)(idx & 31);
        h[idx] = (h[idx] - meaninv[c]) * meaninv[32 + c];
    }
}

extern "C" void kernel_launch(void* const* d_in, const int* in_sizes, int n_in,
                              void* d_out, int out_size, void* d_ws, size_t ws_size,
                              hipStream_t stream) {
    const float* x  = (const float*)d_in[0];
    const int* ei   = (const int*)d_in[1];
    const float* W1 = (const float*)d_in[2];
    const float* b1 = (const float*)d_in[3];
    const float* W3 = (const float*)d_in[4];
    const float* b3 = (const float*)d_in[5];

    const int N = in_sizes[0] / 16;
    const int E = in_sizes[1] / 2;
    const int* src = ei;       // edge_index[0]
    const int* dst = ei + E;   // edge_index[1]

    const int NBUCK = (N + BUCKET_SZ - 1) >> BUCKET_SHIFT;  // 196 for N=100000
    const int CE = (E + NCHUNKS - 1) / NCHUNKS;
    const int BH_TOTAL = NBUCK * NCHUNKS;

    char* ws = (char*)d_ws;
    int*   degi     = (int*)ws;          ws += (size_t)N * 4;
    float* dinv     = (float*)ws;        ws += (size_t)N * 4;
    int*   rowstart = (int*)ws;          ws += (size_t)N * 4;
    int*   bsum2    = (int*)ws;          ws += (size_t)SCAN_BS * 4;
    int*   bh       = (int*)ws;          ws += (size_t)BH_TOTAL * 4;
    int*   bhs      = (int*)ws;          ws += (size_t)BH_TOTAL * 4;
    unsigned int* eb = (unsigned int*)ws; ws += (size_t)E * 4;
    int*   csr_src  = (int*)ws;          ws += (size_t)E * 4;
    __half* xs      = (__half*)ws;       ws += (size_t)N * 16 * 2;
    __half* h2s     = (__half*)ws;       ws += (size_t)N * 32 * 2;
    float* partial  = (float*)ws;        ws += 64 * 4;
    float* meaninv  = (float*)ws;

    float* out = (float*)d_out;  // N*32

    const int NB2 = (BH_TOTAL + SCAN_BS - 1) / SCAN_BS;

    // bucketed edge sort
    kA_bucket_hist<<<NCHUNKS, 256, NBUCK * 4, stream>>>(dst, bh, E, NBUCK, CE);
    k_scan_block<<<NB2, SCAN_BS, 0, stream>>>(bh, bhs, bsum2, BH_TOTAL);
    k_scan_tops<<<1, SCAN_BS, 0, stream>>>(bsum2, NB2);
    k_scan_add<<<NB2, SCAN_BS, 0, stream>>>(bhs, bsum2, BH_TOTAL);
    kC_bucket_scatter<<<NCHUNKS, 256, NBUCK * 4, stream>>>(src, dst, bhs, eb, E, NBUCK, CE);

    // fused: degree hist + block scan -> rowstart/degi/dinv + xs prescale + partial zero
    kDeg_scan_prescale<<<NBUCK, 256, 0, stream>>>(eb, bhs, x, degi, dinv, rowstart, xs,
                                                  partial, N, NBUCK, E);
    kD_fill<<<NBUCK, 256, 0, stream>>>(eb, bhs, rowstart, csr_src, N, NBUCK, E);

    // layer 1: fused gather + MLP
    k_l1_fused<<<(N + 15) / 16, 256, 0, stream>>>(rowstart, degi, csr_src, dinv, xs,
                                                  W1, b1, W3, h2s, N);

    // layer 2 aggregation + bias + relu + stats
    k_gather32_stats<<<(N + 31) / 32, 256, 0, stream>>>(rowstart, degi, csr_src, dinv, h2s,
                                                        b3, out, partial, N);

    // normalizer
    k_finalize<<<1, 64, 0, stream>>>(partial, meaninv, N);
    k_norm<<<((long long)N * 32 + 255) / 256, 256, 0, stream>>>(out, meaninv, N);
}

// Round 8
// 192.420 us; speedup vs baseline: 3.7392x; 1.0111x over previous
//
#include <hip/hip_runtime.h>
#include <hip/hip_fp16.h>

#define EPS 0.01f
#define SCAN_BS 512
#define NCHUNKS 256
#define BUCKET_SHIFT 9
#define BUCKET_SZ (1 << BUCKET_SHIFT)
#define STAGE_CAP 16384  // LDS-staged edges per bucket (avg ~8.2K for E=1.6M, NBUCK=196)

// ---------------- exclusive scan (3-kernel, n <= 512*512) ----------------

__global__ __launch_bounds__(SCAN_BS) void k_scan_block(const int* __restrict__ in,
                                                        int* __restrict__ out,
                                                        int* __restrict__ bsum, int n) {
    __shared__ int sd[SCAN_BS];
    int t = threadIdx.x;
    int gid = blockIdx.x * SCAN_BS + t;
    int v = (gid < n) ? in[gid] : 0;
    sd[t] = v;
    __syncthreads();
    for (int off = 1; off < SCAN_BS; off <<= 1) {
        int x = (t >= off) ? sd[t - off] : 0;
        __syncthreads();
        sd[t] += x;
        __syncthreads();
    }
    if (gid < n) out[gid] = sd[t] - v;  // exclusive
    if (t == SCAN_BS - 1) bsum[blockIdx.x] = sd[t];
}

__global__ __launch_bounds__(SCAN_BS) void k_scan_tops(int* __restrict__ bsum, int nb) {
    __shared__ int sd[SCAN_BS];
    int t = threadIdx.x;
    int v = (t < nb) ? bsum[t] : 0;
    sd[t] = v;
    __syncthreads();
    for (int off = 1; off < SCAN_BS; off <<= 1) {
        int x = (t >= off) ? sd[t - off] : 0;
        __syncthreads();
        sd[t] += x;
        __syncthreads();
    }
    if (t < nb) bsum[t] = sd[t] - v;  // exclusive
}

__global__ __launch_bounds__(SCAN_BS) void k_scan_add(int* __restrict__ out,
                                                      const int* __restrict__ bsum, int n) {
    int gid = blockIdx.x * SCAN_BS + threadIdx.x;
    if (gid < n) out[gid] += bsum[blockIdx.x];
}

// ---------------- bucketed edge sort ----------------

__global__ __launch_bounds__(256) void kA_bucket_hist(const int* __restrict__ dst,
                                                      int* __restrict__ bh, int e,
                                                      int nbuck, int ce) {
    extern __shared__ int hist[];  // nbuck
    int b = blockIdx.x, t = threadIdx.x;
    for (int i = t; i < nbuck; i += 256) hist[i] = 0;
    __syncthreads();
    int lo = b * ce, hi = min(lo + ce, e);
    for (int i = lo + t; i < hi; i += 256) atomicAdd(&hist[dst[i] >> BUCKET_SHIFT], 1);
    __syncthreads();
    for (int i = t; i < nbuck; i += 256) bh[i * NCHUNKS + b] = hist[i];  // [bucket][chunk]
}

__global__ __launch_bounds__(256) void kC_bucket_scatter(const int* __restrict__ src,
                                                         const int* __restrict__ dst,
                                                         const int* __restrict__ bhs,
                                                         unsigned int* __restrict__ eb, int e,
                                                         int nbuck, int ce) {
    extern __shared__ int cur[];  // nbuck
    int b = blockIdx.x, t = threadIdx.x;
    for (int i = t; i < nbuck; i += 256) cur[i] = bhs[i * NCHUNKS + b];
    __syncthreads();
    int lo = b * ce, hi = min(lo + ce, e);
    for (int i = lo + t; i < hi; i += 256) {
        int s = src[i], d = dst[i];
        int pos = atomicAdd(&cur[d >> BUCKET_SHIFT], 1);
        eb[pos] = ((unsigned int)(d & (BUCKET_SZ - 1)) << 23) | (unsigned int)s;
    }
}

// Fused: per-bucket edge stage (LDS) -> degree hist -> block scan ->
// degi/dinv/rowstart -> xs prescale -> csr fill. Block 0 zeroes partial.
__global__ __launch_bounds__(256) void kDeg_fill_prescale(const unsigned int* __restrict__ eb,
                                                          const int* __restrict__ bhs,
                                                          const float* __restrict__ x,
                                                          int* __restrict__ degi,
                                                          float* __restrict__ dinv,
                                                          int* __restrict__ rowstart,
                                                          int* __restrict__ csr_src,
                                                          __half* __restrict__ xs,
                                                          float* __restrict__ partial,
                                                          int n, int nbuck, int e) {
    __shared__ unsigned int ebs[STAGE_CAP];
    __shared__ int hist[BUCKET_SZ];  // later reused as csr cursors
    __shared__ int ps[256];
    __shared__ float dv[BUCKET_SZ];
    int k = blockIdx.x, t = threadIdx.x;
    if (k == 0 && t < 64) partial[t] = 0.f;
    for (int i = t; i < BUCKET_SZ; i += 256) hist[i] = 0;
    __syncthreads();
    int lo = bhs[k * NCHUNKS];
    int hi = (k + 1 < nbuck) ? bhs[(k + 1) * NCHUNKS] : e;
    int cnt = hi - lo;
    bool fits = (cnt <= STAGE_CAP);
    for (int i = t; i < cnt; i += 256) {
        unsigned int p = eb[lo + i];
        if (fits) ebs[i] = p;
        atomicAdd(&hist[p >> 23], 1);
    }
    __syncthreads();
    int a0 = hist[2 * t], a1 = hist[2 * t + 1];
    ps[t] = a0 + a1;
    __syncthreads();
    for (int off = 1; off < 256; off <<= 1) {
        int v = (t >= off) ? ps[t - off] : 0;
        __syncthreads();
        ps[t] += v;
        __syncthreads();
    }
    int excl = ps[t] - (a0 + a1);
    int node0 = k << BUCKET_SHIFT;
    int rs0 = lo + excl, rs1 = lo + excl + a0;
    {
        int nd0 = node0 + 2 * t, nd1 = nd0 + 1;
        float d0 = rsqrtf((float)a0 + 1.0f);
        float d1 = rsqrtf((float)a1 + 1.0f);
        dv[2 * t] = d0;
        dv[2 * t + 1] = d1;
        if (nd0 < n) {
            degi[nd0] = a0;
            dinv[nd0] = d0;
            rowstart[nd0] = rs0;
        }
        if (nd1 < n) {
            degi[nd1] = a1;
            dinv[nd1] = d1;
            rowstart[nd1] = rs1;
        }
    }
    __syncthreads();  // everyone has read a0/a1; reuse hist as cursors
    hist[2 * t] = rs0;
    hist[2 * t + 1] = rs1;
    // prescale: xs[node][c] = x[node][c] * dinv[node]
    for (int i = t; i < BUCKET_SZ * 16; i += 256) {
        int rl = i >> 4;
        int node = node0 + rl;
        if (node < n)
            xs[(size_t)node * 16 + (i & 15)] = __float2half(x[(size_t)node * 16 + (i & 15)] * dv[rl]);
    }
    __syncthreads();
    // csr fill from staged records
    for (int i = t; i < cnt; i += 256) {
        unsigned int p = fits ? ebs[i] : eb[lo + i];
        int dl = (int)(p >> 23);
        int s = (int)(p & 0x7fffffu);
        int pos = atomicAdd(&hist[dl], 1);
        csr_src[pos] = s;
    }
}

// ---------------- fused layer 1: gather16 (half2, 8 chunked slots) + MLP ----------------
// block = 256 threads = 4 waves; 16 nodes per block (4 per wave).
// Output split column-wise: h2sA = cols 0..15, h2sB = cols 16..31 (both * dinv, fp16).

__global__ __launch_bounds__(256) void k_l1_fused(const int* __restrict__ rowstart,
                                                  const int* __restrict__ degi,
                                                  const int* __restrict__ csr_src,
                                                  const float* __restrict__ dinv,
                                                  const __half* __restrict__ xs,
                                                  const float* __restrict__ W1,
                                                  const float* __restrict__ b1,
                                                  const float* __restrict__ W3,
                                                  __half* __restrict__ h2sA,
                                                  __half* __restrict__ h2sB, int n) {
    __shared__ float w1[16 * 64];
    __shared__ float w3[64 * 32];
    __shared__ float bs[64];
    __shared__ __align__(16) float a[16 * 16];
    __shared__ float z[16 * 64];
    int t = threadIdx.x;
    for (int i = t; i < 16 * 64; i += 256) w1[i] = W1[i];
    for (int i = t; i < 64 * 32; i += 256) w3[i] = W3[i];
    if (t < 64) bs[t] = b1[t];

    int row0 = blockIdx.x * 16;
    int wv = t >> 6;
    int lane = t & 63;
    int c2 = lane & 7;        // half2 column pair (cols 2c2, 2c2+1)
    int slot = lane >> 3;     // 0..7 edge slots (contiguous chunks)
    const __half2* xs2 = (const __half2*)xs;

    for (int nid = 0; nid < 4; ++nid) {
        int node = row0 + wv * 4 + nid;
        if (node < n) {
            const int* sp = csr_src + rowstart[node];
            int deg = degi[node];
            int L = (deg + 7) >> 3;
            int base = slot * L;
            int end = min(base + L, deg);
            float ax = 0.f, ay = 0.f, bx = 0.f, by = 0.f;
            int k = base;
            for (; k + 2 <= end; k += 2) {
                int s0 = sp[k], s1 = sp[k + 1];
                float2 v0 = __half22float2(xs2[(size_t)s0 * 8 + c2]);
                float2 v1 = __half22float2(xs2[(size_t)s1 * 8 + c2]);
                ax += v0.x; ay += v0.y;
                bx += v1.x; by += v1.y;
            }
            if (k < end) {
                int s0 = sp[k];
                float2 v0 = __half22float2(xs2[(size_t)s0 * 8 + c2]);
                ax += v0.x; ay += v0.y;
            }
            float sx = ax + bx, sy = ay + by;
            sx += __shfl_xor(sx, 8);  sy += __shfl_xor(sy, 8);
            sx += __shfl_xor(sx, 16); sy += __shfl_xor(sy, 16);
            sx += __shfl_xor(sx, 32); sy += __shfl_xor(sy, 32);
            if (slot == 0) {
                float2 self = __half22float2(xs2[(size_t)node * 8 + c2]);
                float dn = dinv[node];
                int r = wv * 4 + nid;
                ((float2*)(a + r * 16))[c2] = make_float2(dn * (sx + self.x), dn * (sy + self.y));
            }
        }
    }
    __syncthreads();

    // z = relu(a @ W1 + b1)
    for (int i = t; i < 1024; i += 256) {
        int r = i >> 6, c = i & 63;
        float acc = bs[c];
#pragma unroll
        for (int k = 0; k < 16; ++k) acc += a[r * 16 + k] * w1[k * 64 + c];
        z[i] = acc > 0.f ? acc : 0.f;
    }
    __syncthreads();
    // h2s{A,B} = (z @ W3) * dinv  (fp16, column-split)
    for (int i = t; i < 512; i += 256) {
        int r = i >> 5, c = i & 31;
        float acc = 0.f;
#pragma unroll
        for (int k = 0; k < 64; ++k) acc += z[r * 64 + k] * w3[k * 32 + c];
        int row = row0 + r;
        if (row < n) {
            __half hv = __float2half(acc * dinv[row]);
            if (c < 16) h2sA[(size_t)row * 16 + c] = hv;
            else        h2sB[(size_t)row * 16 + (c - 16)] = hv;
        }
    }
}

// ---------------- layer 2 gather, XCD-split column halves + bias + relu + stats --------
// Grid = 2 halves interleaved so blockIdx%8 in {0..3} -> half A (XCDs 0-3),
// {4..7} -> half B (XCDs 4-7). Each XCD's L2 then holds its 3.2 MB array.

__global__ __launch_bounds__(256) void k_gather16x2_stats(const int* __restrict__ rowstart,
                                                          const int* __restrict__ degi,
                                                          const int* __restrict__ csr_src,
                                                          const float* __restrict__ dinv,
                                                          const __half* __restrict__ h2sA,
                                                          const __half* __restrict__ h2sB,
                                                          const float* __restrict__ b3,
                                                          float* __restrict__ out,
                                                          float* __restrict__ partial, int n) {
    int g = blockIdx.x;
    int half = (g >> 2) & 1;
    int nblk = (g >> 3) * 4 + (g & 3);
    int M = (n + 31) >> 5;
    if (nblk >= M) return;
    const __half2* h2 = (const __half2*)(half ? h2sB : h2sA);
    int col0 = half << 4;
    int t = threadIdx.x;
    int lane = t & 63;
    int c2 = lane & 7;        // cols col0+2c2, col0+2c2+1
    int slot = lane >> 3;     // 0..7 (contiguous chunks)
    float2 bias = make_float2(b3[col0 + 2 * c2], b3[col0 + 2 * c2 + 1]);
    float s_x = 0.f, s_y = 0.f, q_x = 0.f, q_y = 0.f;
    for (int it = 0; it < 8; ++it) {
        int node = nblk * 32 + it * 4 + (t >> 6);
        if (node < n) {
            const int* sp = csr_src + rowstart[node];
            int deg = degi[node];
            int L = (deg + 7) >> 3;
            int base = slot * L;
            int end = min(base + L, deg);
            float ax = 0.f, ay = 0.f, bx = 0.f, by = 0.f;
            int k = base;
            for (; k + 2 <= end; k += 2) {
                int s0 = sp[k], s1 = sp[k + 1];
                float2 v0 = __half22float2(h2[(size_t)s0 * 8 + c2]);
                float2 v1 = __half22float2(h2[(size_t)s1 * 8 + c2]);
                ax += v0.x; ay += v0.y;
                bx += v1.x; by += v1.y;
            }
            if (k < end) {
                int s0 = sp[k];
                float2 v0 = __half22float2(h2[(size_t)s0 * 8 + c2]);
                ax += v0.x; ay += v0.y;
            }
            float sx = ax + bx, sy = ay + by;
            sx += __shfl_xor(sx, 8);  sy += __shfl_xor(sy, 8);
            sx += __shfl_xor(sx, 16); sy += __shfl_xor(sy, 16);
            sx += __shfl_xor(sx, 32); sy += __shfl_xor(sy, 32);
            if (slot == 0) {
                float2 self = __half22float2(h2[(size_t)node * 8 + c2]);
                float dn = dinv[node];
                float vx = dn * (sx + self.x) + bias.x;
                float vy = dn * (sy + self.y) + bias.y;
                vx = vx > 0.f ? vx : 0.f;
                vy = vy > 0.f ? vy : 0.f;
                ((float2*)(out + (size_t)node * 32 + col0))[c2] = make_float2(vx, vy);
                s_x += vx; s_y += vy;
                q_x += vx * vx; q_y += vy * vy;
            }
        }
    }
    __shared__ float ls[64], lq[64];
    int wv = t >> 6;
    if (lane < 8) {
        ls[wv * 16 + 2 * c2] = s_x;
        ls[wv * 16 + 2 * c2 + 1] = s_y;
        lq[wv * 16 + 2 * c2] = q_x;
        lq[wv * 16 + 2 * c2 + 1] = q_y;
    }
    __syncthreads();
    if (t < 16) {
        float a = 0.f, b = 0.f;
#pragma unroll
        for (int w = 0; w < 4; ++w) {
            a += ls[w * 16 + t];
            b += lq[w * 16 + t];
        }
        atomicAdd(&partial[col0 + t], a);
        atomicAdd(&partial[32 + col0 + t], b);
    }
}

// ---------------- normalizer ----------------

__global__ void k_finalize(const float* __restrict__ partial, float* __restrict__ meaninv, int n) {
    int t = threadIdx.x;
    if (t < 32) {
        float invn = 1.0f / (float)n;
        float mean = partial[t] * invn;
        float var = partial[32 + t] * invn - mean * mean;
        var = var > EPS ? var : EPS;
        meaninv[t] = mean;
        meaninv[32 + t] = rsqrtf(var);
    }
}

__global__ void k_norm(float* __restrict__ h, const float* __restrict__ meaninv, int n) {
    long long idx = (long long)blockIdx.x * blockDim.x + threadIdx.x;
    if (idx < (long long)n * 32) {
        int c = (int)(idx & 31);
        h[idx] = (h[idx] - meaninv[c]) * meaninv[32 + c];
    }
}

extern "C" void kernel_launch(void* const* d_in, const int* in_sizes, int n_in,
                              void* d_out, int out_size, void* d_ws, size_t ws_size,
                              hipStream_t stream) {
    const float* x  = (const float*)d_in[0];
    const int* ei   = (const int*)d_in[1];
    const float* W1 = (const float*)d_in[2];
    const float* b1 = (const float*)d_in[3];
    const float* W3 = (const float*)d_in[4];
    const float* b3 = (const float*)d_in[5];

    const int N = in_sizes[0] / 16;
    const int E = in_sizes[1] / 2;
    const int* src = ei;       // edge_index[0]
    const int* dst = ei + E;   // edge_index[1]

    const int NBUCK = (N + BUCKET_SZ - 1) >> BUCKET_SHIFT;  // 196 for N=100000
    const int CE = (E + NCHUNKS - 1) / NCHUNKS;
    const int BH_TOTAL = NBUCK * NCHUNKS;

    char* ws = (char*)d_ws;
    int*   degi     = (int*)ws;          ws += (size_t)N * 4;
    float* dinv     = (float*)ws;        ws += (size_t)N * 4;
    int*   rowstart = (int*)ws;          ws += (size_t)N * 4;
    int*   bsum2    = (int*)ws;          ws += (size_t)SCAN_BS * 4;
    int*   bh       = (int*)ws;          ws += (size_t)BH_TOTAL * 4;
    int*   bhs      = (int*)ws;          ws += (size_t)BH_TOTAL * 4;
    unsigned int* eb = (unsigned int*)ws; ws += (size_t)E * 4;
    int*   csr_src  = (int*)ws;          ws += (size_t)E * 4;
    __half* xs      = (__half*)ws;       ws += (size_t)N * 16 * 2;
    __half* h2sA    = (__half*)ws;       ws += (size_t)N * 16 * 2;
    __half* h2sB    = (__half*)ws;       ws += (size_t)N * 16 * 2;
    float* partial  = (float*)ws;        ws += 64 * 4;
    float* meaninv  = (float*)ws;

    float* out = (float*)d_out;  // N*32

    const int NB2 = (BH_TOTAL + SCAN_BS - 1) / SCAN_BS;

    // bucketed edge sort
    kA_bucket_hist<<<NCHUNKS, 256, NBUCK * 4, stream>>>(dst, bh, E, NBUCK, CE);
    k_scan_block<<<NB2, SCAN_BS, 0, stream>>>(bh, bhs, bsum2, BH_TOTAL);
    k_scan_tops<<<1, SCAN_BS, 0, stream>>>(bsum2, NB2);
    k_scan_add<<<NB2, SCAN_BS, 0, stream>>>(bhs, bsum2, BH_TOTAL);
    kC_bucket_scatter<<<NCHUNKS, 256, NBUCK * 4, stream>>>(src, dst, bhs, eb, E, NBUCK, CE);

    // fused: stage bucket edges in LDS -> hist -> scan -> degi/dinv/rowstart
    //        -> xs prescale -> csr fill (+ partial zero)
    kDeg_fill_prescale<<<NBUCK, 256, 0, stream>>>(eb, bhs, x, degi, dinv, rowstart,
                                                  csr_src, xs, partial, N, NBUCK, E);

    // layer 1: fused gather + MLP (writes column-split fp16 h2sA/h2sB)
    k_l1_fused<<<(N + 15) / 16, 256, 0, stream>>>(rowstart, degi, csr_src, dinv, xs,
                                                  W1, b1, W3, h2sA, h2sB, N);

    // layer 2: XCD-split gather + bias + relu + stats
    const int M = (N + 31) >> 5;
    const int G = ((M + 3) / 4) * 8;
    k_gather16x2_stats<<<G, 256, 0, stream>>>(rowstart, degi, csr_src, dinv, h2sA, h2sB,
                                              b3, out, partial, N);

    // normalizer
    k_finalize<<<1, 64, 0, stream>>>(partial, meaninv, N);
    k_norm<<<((long long)N * 32 + 255) / 256, 256, 0, stream>>>(out, meaninv, N);
}